// Round 1
// baseline (4067.854 us; speedup 1.0000x reference)
//
#include <hip/hip_runtime.h>
#include <math.h>

constexpr int BLK = 256;

static inline int cdiv(long a, long b) { return (int)((a + b - 1) / b); }

// ---------------- GEMM h = x @ W (+ fused attention dots a_src, a_dst) -------
// Thread = (node, 4-wide f-tile). TPN = DOUT/4 threads per node, sub-wave
// shuffle reduction for the per-node dot products h.a_s / h.a_d.
template <int DIN, int DOUT>
__global__ void gemm_attn(const float* __restrict__ x, const float* __restrict__ W,
                          const float* __restrict__ a_s, const float* __restrict__ a_d,
                          float* __restrict__ h, float* __restrict__ asrc,
                          float* __restrict__ adst, int N) {
    constexpr int TPN = DOUT / 4;
    int t = blockIdx.x * blockDim.x + threadIdx.x;
    int n = t / TPN;
    if (n >= N) return;
    int fq = (t % TPN) * 4;
    const float* xr = x + (long)n * DIN;
    float4 acc = {0.f, 0.f, 0.f, 0.f};
#pragma unroll 8
    for (int k = 0; k < DIN; ++k) {
        float xv = xr[k];
        float4 wv = *(const float4*)(W + (long)k * DOUT + fq);
        acc.x += xv * wv.x; acc.y += xv * wv.y;
        acc.z += xv * wv.z; acc.w += xv * wv.w;
    }
    *(float4*)(h + (long)n * DOUT + fq) = acc;

    float4 asv = *(const float4*)(a_s + fq);
    float4 adv = *(const float4*)(a_d + fq);
    float s = acc.x * asv.x + acc.y * asv.y + acc.z * asv.z + acc.w * asv.w;
    float d = acc.x * adv.x + acc.y * adv.y + acc.z * adv.z + acc.w * adv.w;
#pragma unroll
    for (int off = TPN / 2; off > 0; off >>= 1) {
        s += __shfl_xor(s, off, TPN);
        d += __shfl_xor(d, off, TPN);
    }
    if ((t % TPN) == 0) { asrc[n] = s; adst[n] = d; }
}

// ---------------- edge pass 1: score + segment max (flipped-uint atomicMax) --
__device__ __forceinline__ unsigned flt_flip(float f) {
    unsigned u = __float_as_uint(f);
    return (u & 0x80000000u) ? ~u : (u | 0x80000000u);
}
__device__ __forceinline__ float flt_unflip(unsigned e) {
    return (e & 0x80000000u) ? __uint_as_float(e ^ 0x80000000u) : __uint_as_float(~e);
}

__global__ void edge_score_max(const int* __restrict__ src, const int* __restrict__ dst,
                               const float* __restrict__ asrc, const float* __restrict__ adst,
                               float* __restrict__ e, unsigned* __restrict__ m,
                               int ET, int E) {
    int j = blockIdx.x * blockDim.x + threadIdx.x;
    if (j >= ET) return;
    int s = (j < E) ? src[j] : (j - E);
    int d = (j < E) ? dst[j] : (j - E);
    float v = asrc[s] + adst[d];
    v = v > 0.f ? v : 0.2f * v;          // leaky_relu(0.2)
    e[j] = v;
    atomicMax(&m[d], flt_flip(v));
}

// ---------------- edge pass 2: w = exp(e - m[dst]); denom += w ---------------
__global__ void edge_exp_denom(const int* __restrict__ dst, float* __restrict__ e,
                               const unsigned* __restrict__ m, float* __restrict__ denom,
                               int ET, int E) {
    int j = blockIdx.x * blockDim.x + threadIdx.x;
    if (j >= ET) return;
    int d = (j < E) ? dst[j] : (j - E);
    float w = __expf(e[j] - flt_unflip(m[d]));
    e[j] = w;                             // overwrite score with weight
    atomicAdd(&denom[d], w);
}

__global__ void recip_k(float* __restrict__ denom, int N) {
    int i = blockIdx.x * blockDim.x + threadIdx.x;
    if (i < N) denom[i] = 1.f / denom[i];
}

// ---------------- edge pass 3: out[dst] += alpha * h[src] --------------------
template <int DOUT>
__global__ void edge_scatter(const int* __restrict__ src, const int* __restrict__ dst,
                             const float* __restrict__ w, const float* __restrict__ inv,
                             const float* __restrict__ h, float* __restrict__ out,
                             int ET, int E) {
    constexpr int TPE = DOUT / 4;
    long t = (long)blockIdx.x * blockDim.x + threadIdx.x;
    long j = t / TPE;
    if (j >= ET) return;
    int fq = (int)(t % TPE) * 4;
    int s = (j < E) ? src[j] : (int)(j - E);
    int d = (j < E) ? dst[j] : (int)(j - E);
    float alpha = w[j] * inv[d];
    float4 hv = *(const float4*)(h + (long)s * DOUT + fq);
    float* o = out + (long)d * DOUT + fq;
    atomicAdd(o + 0, alpha * hv.x);
    atomicAdd(o + 1, alpha * hv.y);
    atomicAdd(o + 2, alpha * hv.z);
    atomicAdd(o + 3, alpha * hv.w);
}

// ---------------- epilogue: +bias, leaky(0.01), BN statistics ----------------
template <int DOUT>
__global__ void bias_act_stats(float* __restrict__ y, const float* __restrict__ b,
                               float* __restrict__ bnsum, float* __restrict__ bnsq, int N) {
    __shared__ float ssum[DOUT];
    __shared__ float ssq[DOUT];
    for (int i = threadIdx.x; i < DOUT; i += blockDim.x) { ssum[i] = 0.f; ssq[i] = 0.f; }
    __syncthreads();
    int f = threadIdx.x % DOUT;          // stride is a multiple of DOUT -> f constant
    float bv = b[f];
    float lsum = 0.f, lsq = 0.f;
    long total = (long)N * DOUT;
    long stride = (long)gridDim.x * blockDim.x;
    for (long t = (long)blockIdx.x * blockDim.x + threadIdx.x; t < total; t += stride) {
        float v = y[t] + bv;
        v = v > 0.f ? v : 0.01f * v;
        y[t] = v;
        lsum += v; lsq += v * v;
    }
    atomicAdd(&ssum[f], lsum);
    atomicAdd(&ssq[f], lsq);
    __syncthreads();
    for (int i = threadIdx.x; i < DOUT; i += blockDim.x) {
        atomicAdd(&bnsum[i], ssum[i]);
        atomicAdd(&bnsq[i], ssq[i]);
    }
}

__global__ void bn_coef(const float* __restrict__ bnsum, const float* __restrict__ bnsq,
                        const float* __restrict__ g, const float* __restrict__ be,
                        float* __restrict__ coef, int DOUT, float invN) {
    int f = threadIdx.x;
    if (f >= DOUT) return;
    float mu = bnsum[f] * invN;
    float var = bnsq[f] * invN - mu * mu;   // biased variance, matches reference
    float a = g[f] * rsqrtf(var + 1e-5f);
    coef[f] = a;
    coef[DOUT + f] = be[f] - mu * a;
}

template <int DOUT>
__global__ void bn_apply(float* __restrict__ y, const float* __restrict__ coef, long nq) {
    long t = (long)blockIdx.x * blockDim.x + threadIdx.x;
    if (t >= nq) return;
    int fq = (int)(t % (DOUT / 4)) * 4;
    float4 a = *(const float4*)(coef + fq);
    float4 c = *(const float4*)(coef + DOUT + fq);
    float4 v = *(float4*)(y + t * 4);
    v.x = v.x * a.x + c.x; v.y = v.y * a.y + c.y;
    v.z = v.z * a.z + c.z; v.w = v.w * a.w + c.w;
    *(float4*)(y + t * 4) = v;
}

// ---------------- global_add_pool over batch ---------------------------------
__global__ void pool_k(const float* __restrict__ h, const int* __restrict__ batch,
                       float* __restrict__ pooled, int N) {
    long t = (long)blockIdx.x * blockDim.x + threadIdx.x;
    if (t >= (long)N * 64) return;
    int n = (int)(t >> 6);
    int f = (int)(t & 63);
    atomicAdd(&pooled[(long)batch[n] * 64 + f], h[t]);
}

// ---------------- MLP head: leaky(pooled@Wf+bf) -> sigmoid(@Wc+bc) -----------
__global__ void head_k(const float* __restrict__ pooled, const float* __restrict__ Wf,
                       const float* __restrict__ bf, const float* __restrict__ Wc,
                       const float* __restrict__ bc, float* __restrict__ out) {
    int g = blockIdx.x;
    int t = threadIdx.x;        // 64 threads
    __shared__ float p[64];
    __shared__ float z[32];
    p[t] = pooled[(long)g * 64 + t];
    __syncthreads();
    if (t < 32) {
        float acc = bf[t];
#pragma unroll
        for (int f = 0; f < 64; ++f) acc += p[f] * Wf[f * 32 + t];
        z[t] = acc > 0.f ? acc : 0.01f * acc;
    }
    __syncthreads();
    if (t < 8) {
        float acc = bc[t];
#pragma unroll
        for (int o = 0; o < 32; ++o) acc += z[o] * Wc[o * 8 + t];
        out[(long)g * 8 + t] = 1.f / (1.f + __expf(-acc));
    }
}

extern "C" void kernel_launch(void* const* d_in, const int* in_sizes, int n_in,
                              void* d_out, int out_size, void* d_ws, size_t ws_size,
                              hipStream_t stream) {
    const float* x   = (const float*)d_in[0];
    const int* ei    = (const int*)d_in[1];
    const int* batch = (const int*)d_in[2];
    const int N  = in_sizes[2];
    const int E  = in_sizes[1] / 2;
    const int ET = E + N;
    const int G  = out_size / 8;
    const int* src = ei;
    const int* dst = ei + E;

    const float *W[4], *as_[4], *ad_[4], *bb[4], *gg[4], *be_[4];
    for (int i = 0; i < 4; ++i) {
        W[i]   = (const float*)d_in[3 + 6 * i];
        as_[i] = (const float*)d_in[4 + 6 * i];
        ad_[i] = (const float*)d_in[5 + 6 * i];
        bb[i]  = (const float*)d_in[6 + 6 * i];
        gg[i]  = (const float*)d_in[7 + 6 * i];
        be_[i] = (const float*)d_in[8 + 6 * i];
    }
    const float* Wf = (const float*)d_in[27];
    const float* bf = (const float*)d_in[28];
    const float* Wc = (const float*)d_in[29];
    const float* bc = (const float*)d_in[30];

    float* ws = (float*)d_ws;
    long off = 0;
    auto alloc = [&](long nelem) { float* p = ws + off; off += (nelem + 3) & ~3L; return p; };
    float* A      = alloc((long)N * 128);   // h (post-GEMM)
    float* B      = alloc((long)N * 128);   // layer io / aggregation target
    float* ew     = alloc(ET);              // edge score, then weight
    float* mbuf   = alloc(N);               // flipped-uint segment max
    float* denom  = alloc(N);               // softmax denom, then reciprocal
    float* asrc   = alloc(N);
    float* adst   = alloc(N);
    float* bnsum  = alloc(128);
    float* bnsq   = alloc(128);
    float* coef   = alloc(256);
    float* pooled = alloc((long)G * 64);
    (void)ws_size; (void)n_in;

#define LAYER(i, DIN, DOUT, INPTR)                                                        \
    do {                                                                                  \
        hipMemsetAsync(mbuf, 0, N * sizeof(float), stream);                               \
        hipMemsetAsync(denom, 0, N * sizeof(float), stream);                              \
        hipMemsetAsync(bnsum, 0, 128 * sizeof(float), stream);                            \
        hipMemsetAsync(bnsq, 0, 128 * sizeof(float), stream);                             \
        gemm_attn<DIN, DOUT><<<cdiv((long)N * (DOUT / 4), BLK), BLK, 0, stream>>>(        \
            INPTR, W[i], as_[i], ad_[i], A, asrc, adst, N);                               \
        hipMemsetAsync(B, 0, (long)N * DOUT * sizeof(float), stream);                     \
        edge_score_max<<<cdiv(ET, BLK), BLK, 0, stream>>>(src, dst, asrc, adst, ew,       \
                                                          (unsigned*)mbuf, ET, E);        \
        edge_exp_denom<<<cdiv(ET, BLK), BLK, 0, stream>>>(dst, ew, (const unsigned*)mbuf, \
                                                          denom, ET, E);                  \
        recip_k<<<cdiv(N, BLK), BLK, 0, stream>>>(denom, N);                              \
        edge_scatter<DOUT><<<cdiv((long)ET * (DOUT / 4), BLK), BLK, 0, stream>>>(         \
            src, dst, ew, denom, A, B, ET, E);                                            \
        bias_act_stats<DOUT><<<1024, BLK, 0, stream>>>(B, bb[i], bnsum, bnsq, N);         \
        bn_coef<<<1, 128, 0, stream>>>(bnsum, bnsq, gg[i], be_[i], coef, DOUT, 1.f / N);  \
        bn_apply<DOUT><<<cdiv((long)N * DOUT / 4, BLK), BLK, 0, stream>>>(B, coef,        \
                                                                (long)N * DOUT / 4);      \
    } while (0)

    LAYER(0, 128, 32, x);
    LAYER(1, 32, 64, B);
    LAYER(2, 64, 128, B);
    LAYER(3, 128, 64, B);
#undef LAYER

    hipMemsetAsync(pooled, 0, (long)G * 64 * sizeof(float), stream);
    pool_k<<<cdiv((long)N * 64, BLK), BLK, 0, stream>>>(B, batch, pooled, N);
    head_k<<<G, 64, 0, stream>>>(pooled, Wf, bf, Wc, bc, (float*)d_out);
}

// Round 2
// 863.965 us; speedup vs baseline: 4.7084x; 4.7084x over previous
//
#include <hip/hip_runtime.h>
#include <math.h>

constexpr int BLK = 256;

static inline int cdiv(long a, long b) { return (int)((a + b - 1) / b); }

// ---------------- GEMM h = x @ W (+ fused attention dots a_src, a_dst) -------
template <int DIN, int DOUT>
__global__ void gemm_attn(const float* __restrict__ x, const float* __restrict__ W,
                          const float* __restrict__ a_s, const float* __restrict__ a_d,
                          float* __restrict__ h, float* __restrict__ asrc,
                          float* __restrict__ adst, int N) {
    constexpr int TPN = DOUT / 4;
    int t = blockIdx.x * blockDim.x + threadIdx.x;
    int n = t / TPN;
    if (n >= N) return;
    int fq = (t % TPN) * 4;
    const float* xr = x + (long)n * DIN;
    float4 acc = {0.f, 0.f, 0.f, 0.f};
#pragma unroll 8
    for (int k = 0; k < DIN; ++k) {
        float xv = xr[k];
        float4 wv = *(const float4*)(W + (long)k * DOUT + fq);
        acc.x += xv * wv.x; acc.y += xv * wv.y;
        acc.z += xv * wv.z; acc.w += xv * wv.w;
    }
    *(float4*)(h + (long)n * DOUT + fq) = acc;

    float4 asv = *(const float4*)(a_s + fq);
    float4 adv = *(const float4*)(a_d + fq);
    float s = acc.x * asv.x + acc.y * asv.y + acc.z * asv.z + acc.w * asv.w;
    float d = acc.x * adv.x + acc.y * adv.y + acc.z * adv.z + acc.w * adv.w;
#pragma unroll
    for (int off = TPN / 2; off > 0; off >>= 1) {
        s += __shfl_xor(s, off, TPN);
        d += __shfl_xor(d, off, TPN);
    }
    if ((t % TPN) == 0) { asrc[n] = s; adst[n] = d; }
}

// ---------------- CSR build: histogram -> exclusive scan -> fill -------------
__global__ void hist_k(const int* __restrict__ dst, int* __restrict__ deg, int ET, int E) {
    int j = blockIdx.x * blockDim.x + threadIdx.x;
    if (j >= ET) return;
    int d = (j < E) ? dst[j] : (j - E);
    atomicAdd(&deg[d], 1);
}

__global__ void scan_block_k(const int* __restrict__ deg, int* __restrict__ off,
                             int* __restrict__ bsum, int N) {
    __shared__ int s[BLK];
    int i = blockIdx.x * BLK + threadIdx.x;
    int v = (i < N) ? deg[i] : 0;
    s[threadIdx.x] = v;
    __syncthreads();
    for (int o = 1; o < BLK; o <<= 1) {
        int t = (threadIdx.x >= o) ? s[threadIdx.x - o] : 0;
        __syncthreads();
        s[threadIdx.x] += t;
        __syncthreads();
    }
    if (i < N) off[i] = s[threadIdx.x] - v;       // exclusive
    if (threadIdx.x == BLK - 1) bsum[blockIdx.x] = s[BLK - 1];
}

__global__ void scan_sums_k(int* __restrict__ bsum, int nblk, int* __restrict__ off_end,
                            int total) {
    __shared__ int s[BLK];
    int v = (threadIdx.x < nblk) ? bsum[threadIdx.x] : 0;
    s[threadIdx.x] = v;
    __syncthreads();
    for (int o = 1; o < BLK; o <<= 1) {
        int t = (threadIdx.x >= o) ? s[threadIdx.x - o] : 0;
        __syncthreads();
        s[threadIdx.x] += t;
        __syncthreads();
    }
    if (threadIdx.x < nblk) bsum[threadIdx.x] = s[threadIdx.x] - v;   // exclusive
    if (threadIdx.x == 0) *off_end = total;
}

__global__ void scan_add_k(int* __restrict__ off, const int* __restrict__ bsum, int N) {
    int i = blockIdx.x * BLK + threadIdx.x;
    if (i < N) off[i] += bsum[blockIdx.x];
}

__global__ void fill_k(const int* __restrict__ src, const int* __restrict__ dst,
                       const int* __restrict__ off, int* __restrict__ fill,
                       int* __restrict__ csr_src, int ET, int E) {
    int j = blockIdx.x * blockDim.x + threadIdx.x;
    if (j >= ET) return;
    int d = (j < E) ? dst[j] : (j - E);
    int s = (j < E) ? src[j] : (j - E);
    int pos = off[d] + atomicAdd(&fill[d], 1);
    csr_src[pos] = s;
}

// ---------------- per-node softmax over incoming edges (no atomics) ----------
__global__ void node_softmax_k(const int* __restrict__ off, const int* __restrict__ csr_src,
                               const float* __restrict__ asrc, const float* __restrict__ adst,
                               float* __restrict__ alpha, int N) {
    int d = blockIdx.x * blockDim.x + threadIdx.x;
    if (d >= N) return;
    int p0 = off[d], p1 = off[d + 1];
    float ad = adst[d];
    float mx = -1e30f;
    for (int p = p0; p < p1; ++p) {
        float e = asrc[csr_src[p]] + ad;
        e = e > 0.f ? e : 0.2f * e;            // leaky_relu(0.2)
        alpha[p] = e;
        mx = fmaxf(mx, e);
    }
    float sum = 0.f;
    for (int p = p0; p < p1; ++p) {
        float w = __expf(alpha[p] - mx);
        sum += w;
        alpha[p] = w;
    }
    float inv = 1.f / sum;                      // self-loop guarantees sum > 0
    for (int p = p0; p < p1; ++p) alpha[p] *= inv;
}

// ---------------- gather-aggregate + bias + leaky(0.01) (no atomics) ---------
template <int DOUT>
__global__ void gather_bias_act(const int* __restrict__ off, const int* __restrict__ csr_src,
                                const float* __restrict__ alpha, const float* __restrict__ h,
                                const float* __restrict__ b, float* __restrict__ out, int N) {
    constexpr int TPE = DOUT / 4;
    long t = (long)blockIdx.x * blockDim.x + threadIdx.x;
    int d = (int)(t / TPE);
    if (d >= N) return;
    int fq = (int)(t % TPE) * 4;
    int p0 = off[d], p1 = off[d + 1];
    float4 acc = {0.f, 0.f, 0.f, 0.f};
    for (int p = p0; p < p1; ++p) {
        float a = alpha[p];
        float4 hv = *(const float4*)(h + (long)csr_src[p] * DOUT + fq);
        acc.x += a * hv.x; acc.y += a * hv.y;
        acc.z += a * hv.z; acc.w += a * hv.w;
    }
    float4 bv = *(const float4*)(b + fq);
    acc.x += bv.x; acc.y += bv.y; acc.z += bv.z; acc.w += bv.w;
    acc.x = acc.x > 0.f ? acc.x : 0.01f * acc.x;
    acc.y = acc.y > 0.f ? acc.y : 0.01f * acc.y;
    acc.z = acc.z > 0.f ? acc.z : 0.01f * acc.z;
    acc.w = acc.w > 0.f ? acc.w : 0.01f * acc.w;
    *(float4*)(out + (long)d * DOUT + fq) = acc;
}

// ---------------- BN statistics (read-only pass) -----------------------------
template <int DOUT>
__global__ void stats_k(const float* __restrict__ y, float* __restrict__ bnsum,
                        float* __restrict__ bnsq, int N) {
    __shared__ float ssum[DOUT];
    __shared__ float ssq[DOUT];
    for (int i = threadIdx.x; i < DOUT; i += blockDim.x) { ssum[i] = 0.f; ssq[i] = 0.f; }
    __syncthreads();
    int f = threadIdx.x % DOUT;                 // blockDim multiple of DOUT -> constant f
    float lsum = 0.f, lsq = 0.f;
    long total = (long)N * DOUT;
    long stride = (long)gridDim.x * blockDim.x;
    for (long t = (long)blockIdx.x * blockDim.x + threadIdx.x; t < total; t += stride) {
        float v = y[t];
        lsum += v; lsq += v * v;
    }
    atomicAdd(&ssum[f], lsum);
    atomicAdd(&ssq[f], lsq);
    __syncthreads();
    for (int i = threadIdx.x; i < DOUT; i += blockDim.x) {
        atomicAdd(&bnsum[i], ssum[i]);
        atomicAdd(&bnsq[i], ssq[i]);
    }
}

__global__ void bn_coef(const float* __restrict__ bnsum, const float* __restrict__ bnsq,
                        const float* __restrict__ g, const float* __restrict__ be,
                        float* __restrict__ coef, int DOUT, float invN) {
    int f = threadIdx.x;
    if (f >= DOUT) return;
    float mu = bnsum[f] * invN;
    float var = bnsq[f] * invN - mu * mu;       // biased variance, matches reference
    float a = g[f] * rsqrtf(var + 1e-5f);
    coef[f] = a;
    coef[DOUT + f] = be[f] - mu * a;
}

template <int DOUT>
__global__ void bn_apply(float* __restrict__ y, const float* __restrict__ coef, long nq) {
    long t = (long)blockIdx.x * blockDim.x + threadIdx.x;
    if (t >= nq) return;
    int fq = (int)(t % (DOUT / 4)) * 4;
    float4 a = *(const float4*)(coef + fq);
    float4 c = *(const float4*)(coef + DOUT + fq);
    float4 v = *(float4*)(y + t * 4);
    v.x = v.x * a.x + c.x; v.y = v.y * a.y + c.y;
    v.z = v.z * a.z + c.z; v.w = v.w * a.w + c.w;
    *(float4*)(y + t * 4) = v;
}

// ---------------- pool over contiguous per-graph ranges (batch is sorted) ----
__global__ void grange_k(const int* __restrict__ batch, int* __restrict__ gs,
                         int* __restrict__ ge, int N) {
    int n = blockIdx.x * blockDim.x + threadIdx.x;
    if (n >= N) return;
    int b = batch[n];
    atomicMin(&gs[b], n);
    atomicMax(&ge[b], n);
}

__global__ void pool_range_k(const float* __restrict__ h, const int* __restrict__ gs,
                             const int* __restrict__ ge, float* __restrict__ pooled) {
    int g = blockIdx.x;
    int f = threadIdx.x;                        // 64 threads
    int s0 = gs[g], s1 = ge[g];
    float acc = 0.f;
    if (s0 <= s1)
        for (int n = s0; n <= s1; ++n) acc += h[(long)n * 64 + f];
    pooled[(long)g * 64 + f] = acc;
}

// ---------------- MLP head ----------------------------------------------------
__global__ void head_k(const float* __restrict__ pooled, const float* __restrict__ Wf,
                       const float* __restrict__ bf, const float* __restrict__ Wc,
                       const float* __restrict__ bc, float* __restrict__ out) {
    int g = blockIdx.x;
    int t = threadIdx.x;                        // 64 threads
    __shared__ float p[64];
    __shared__ float z[32];
    p[t] = pooled[(long)g * 64 + t];
    __syncthreads();
    if (t < 32) {
        float acc = bf[t];
#pragma unroll
        for (int f = 0; f < 64; ++f) acc += p[f] * Wf[f * 32 + t];
        z[t] = acc > 0.f ? acc : 0.01f * acc;
    }
    __syncthreads();
    if (t < 8) {
        float acc = bc[t];
#pragma unroll
        for (int o = 0; o < 32; ++o) acc += z[o] * Wc[o * 8 + t];
        out[(long)g * 8 + t] = 1.f / (1.f + __expf(-acc));
    }
}

extern "C" void kernel_launch(void* const* d_in, const int* in_sizes, int n_in,
                              void* d_out, int out_size, void* d_ws, size_t ws_size,
                              hipStream_t stream) {
    const float* x   = (const float*)d_in[0];
    const int* ei    = (const int*)d_in[1];
    const int* batch = (const int*)d_in[2];
    const int N  = in_sizes[2];
    const int E  = in_sizes[1] / 2;
    const int ET = E + N;
    const int G  = out_size / 8;
    const int* src = ei;
    const int* dst = ei + E;

    const float *W[4], *as_[4], *ad_[4], *bb[4], *gg[4], *be_[4];
    for (int i = 0; i < 4; ++i) {
        W[i]   = (const float*)d_in[3 + 6 * i];
        as_[i] = (const float*)d_in[4 + 6 * i];
        ad_[i] = (const float*)d_in[5 + 6 * i];
        bb[i]  = (const float*)d_in[6 + 6 * i];
        gg[i]  = (const float*)d_in[7 + 6 * i];
        be_[i] = (const float*)d_in[8 + 6 * i];
    }
    const float* Wf = (const float*)d_in[27];
    const float* bf = (const float*)d_in[28];
    const float* Wc = (const float*)d_in[29];
    const float* bc = (const float*)d_in[30];

    float* ws = (float*)d_ws;
    long off_ = 0;
    auto alloc = [&](long nelem) { float* p = ws + off_; off_ += (nelem + 3) & ~3L; return p; };
    float* A       = alloc((long)N * 128);   // h (post-GEMM)
    float* B       = alloc((long)N * 128);   // layer output / next input
    float* alpha   = alloc(ET);              // edge weights, CSR order
    float* asrc    = alloc(N);
    float* adst    = alloc(N);
    float* bnstats = alloc(256);             // bnsum(128) + bnsq(128), contiguous
    float* coef    = alloc(256);
    float* pooled  = alloc((long)G * 64);
    int* deg     = (int*)alloc(N);
    int* off     = (int*)alloc(N + 1);
    int* bsum    = (int*)alloc(BLK);
    int* fillc   = (int*)alloc(N);
    int* csr_src = (int*)alloc(ET);
    int* gs      = (int*)alloc(G);
    int* ge      = (int*)alloc(G);
    float* bnsum = bnstats;
    float* bnsq  = bnstats + 128;
    (void)ws_size; (void)n_in;

    const int nblk = cdiv(N, BLK);           // 196 <= 256

    // ---- CSR build (graph is static across layers; rebuilt every call) ----
    hipMemsetAsync(deg, 0, N * sizeof(int), stream);
    hipMemsetAsync(fillc, 0, N * sizeof(int), stream);
    hist_k<<<cdiv(ET, BLK), BLK, 0, stream>>>(dst, deg, ET, E);
    scan_block_k<<<nblk, BLK, 0, stream>>>(deg, off, bsum, N);
    scan_sums_k<<<1, BLK, 0, stream>>>(bsum, nblk, off + N, ET);
    scan_add_k<<<nblk, BLK, 0, stream>>>(off, bsum, N);
    fill_k<<<cdiv(ET, BLK), BLK, 0, stream>>>(src, dst, off, fillc, csr_src, ET, E);

    // ---- per-graph node ranges for pooling (batch is sorted) ----
    hipMemsetAsync(gs, 0x7f, G * sizeof(int), stream);    // ~INT_MAX
    hipMemsetAsync(ge, 0xff, G * sizeof(int), stream);    // -1
    grange_k<<<cdiv(N, BLK), BLK, 0, stream>>>(batch, gs, ge, N);

#define LAYER(i, DIN, DOUT, INPTR)                                                        \
    do {                                                                                  \
        hipMemsetAsync(bnstats, 0, 256 * sizeof(float), stream);                          \
        gemm_attn<DIN, DOUT><<<cdiv((long)N * (DOUT / 4), BLK), BLK, 0, stream>>>(        \
            INPTR, W[i], as_[i], ad_[i], A, asrc, adst, N);                               \
        node_softmax_k<<<cdiv(N, BLK), BLK, 0, stream>>>(off, csr_src, asrc, adst,        \
                                                         alpha, N);                       \
        gather_bias_act<DOUT><<<cdiv((long)N * (DOUT / 4), BLK), BLK, 0, stream>>>(       \
            off, csr_src, alpha, A, bb[i], B, N);                                         \
        stats_k<DOUT><<<512, BLK, 0, stream>>>(B, bnsum, bnsq, N);                        \
        bn_coef<<<1, 128, 0, stream>>>(bnsum, bnsq, gg[i], be_[i], coef, DOUT, 1.f / N);  \
        bn_apply<DOUT><<<cdiv((long)N * DOUT / 4, BLK), BLK, 0, stream>>>(B, coef,        \
                                                                (long)N * DOUT / 4);      \
    } while (0)

    LAYER(0, 128, 32, x);
    LAYER(1, 32, 64, B);
    LAYER(2, 64, 128, B);
    LAYER(3, 128, 64, B);
#undef LAYER

    pool_range_k<<<G, 64, 0, stream>>>(B, gs, ge, pooled);
    head_k<<<G, 64, 0, stream>>>(pooled, Wf, bf, Wc, bc, (float*)d_out);
}

// Round 3
// 707.834 us; speedup vs baseline: 5.7469x; 1.2206x over previous
//
#include <hip/hip_runtime.h>
#include <math.h>

constexpr int BLK = 256;

static inline int cdiv(long a, long b) { return (int)((a + b - 1) / b); }

// ---------------- bf16 helpers (RNE) -----------------------------------------
__device__ __forceinline__ unsigned short f2bf(float f) {
    unsigned u = __float_as_uint(f);
    unsigned r = u + 0x7fffu + ((u >> 16) & 1u);
    return (unsigned short)(r >> 16);
}
__device__ __forceinline__ float bf2f(unsigned short s) {
    return __uint_as_float(((unsigned)s) << 16);
}

// ---------------- GEMM h = x @ W (+ attention dots), h stored bf16 -----------
template <int DIN, int DOUT>
__global__ void gemm_attn(const float* __restrict__ x, const float* __restrict__ W,
                          const float* __restrict__ a_s, const float* __restrict__ a_d,
                          unsigned short* __restrict__ hb, float* __restrict__ asrc,
                          float* __restrict__ adst, int N) {
    constexpr int TPN = DOUT / 4;
    int t = blockIdx.x * blockDim.x + threadIdx.x;
    int n = t / TPN;
    if (n >= N) return;
    int fq = (t % TPN) * 4;
    const float* xr = x + (long)n * DIN;
    float4 acc = {0.f, 0.f, 0.f, 0.f};
#pragma unroll 8
    for (int k = 0; k < DIN; ++k) {
        float xv = xr[k];
        float4 wv = *(const float4*)(W + (long)k * DOUT + fq);
        acc.x += xv * wv.x; acc.y += xv * wv.y;
        acc.z += xv * wv.z; acc.w += xv * wv.w;
    }
    ushort4 hw = {f2bf(acc.x), f2bf(acc.y), f2bf(acc.z), f2bf(acc.w)};
    *(ushort4*)(hb + (long)n * DOUT + fq) = hw;

    float4 asv = *(const float4*)(a_s + fq);
    float4 adv = *(const float4*)(a_d + fq);
    float s = acc.x * asv.x + acc.y * asv.y + acc.z * asv.z + acc.w * asv.w;
    float d = acc.x * adv.x + acc.y * adv.y + acc.z * adv.z + acc.w * adv.w;
#pragma unroll
    for (int off = TPN / 2; off > 0; off >>= 1) {
        s += __shfl_xor(s, off, TPN);
        d += __shfl_xor(d, off, TPN);
    }
    if ((t % TPN) == 0) { asrc[n] = s; adst[n] = d; }
}

// ---------------- CSR build: histogram -> exclusive scan -> fill -------------
__global__ void hist_k(const int* __restrict__ dst, int* __restrict__ deg, int ET, int E) {
    int j = blockIdx.x * blockDim.x + threadIdx.x;
    if (j >= ET) return;
    int d = (j < E) ? dst[j] : (j - E);
    atomicAdd(&deg[d], 1);
}

__global__ void scan_block_k(const int* __restrict__ deg, int* __restrict__ off,
                             int* __restrict__ bsum, int N) {
    __shared__ int s[BLK];
    int i = blockIdx.x * BLK + threadIdx.x;
    int v = (i < N) ? deg[i] : 0;
    s[threadIdx.x] = v;
    __syncthreads();
    for (int o = 1; o < BLK; o <<= 1) {
        int t = (threadIdx.x >= o) ? s[threadIdx.x - o] : 0;
        __syncthreads();
        s[threadIdx.x] += t;
        __syncthreads();
    }
    if (i < N) off[i] = s[threadIdx.x] - v;       // exclusive
    if (threadIdx.x == BLK - 1) bsum[blockIdx.x] = s[BLK - 1];
}

__global__ void scan_sums_k(int* __restrict__ bsum, int nblk, int* __restrict__ off_end,
                            int total) {
    __shared__ int s[BLK];
    int v = (threadIdx.x < nblk) ? bsum[threadIdx.x] : 0;
    s[threadIdx.x] = v;
    __syncthreads();
    for (int o = 1; o < BLK; o <<= 1) {
        int t = (threadIdx.x >= o) ? s[threadIdx.x - o] : 0;
        __syncthreads();
        s[threadIdx.x] += t;
        __syncthreads();
    }
    if (threadIdx.x < nblk) bsum[threadIdx.x] = s[threadIdx.x] - v;   // exclusive
    if (threadIdx.x == 0) *off_end = total;
}

__global__ void scan_add_k(int* __restrict__ off, const int* __restrict__ bsum, int N) {
    int i = blockIdx.x * BLK + threadIdx.x;
    if (i < N) off[i] += bsum[blockIdx.x];
}

__global__ void fill_k(const int* __restrict__ src, const int* __restrict__ dst,
                       const int* __restrict__ off, int* __restrict__ fill,
                       int* __restrict__ csr_src, int ET, int E) {
    int j = blockIdx.x * blockDim.x + threadIdx.x;
    if (j >= ET) return;
    int d = (j < E) ? dst[j] : (j - E);
    int s = (j < E) ? src[j] : (j - E);
    int pos = off[d] + atomicAdd(&fill[d], 1);
    csr_src[pos] = s;
}

// ---------------- fused softmax + gather + bias + leaky(0.01) ----------------
// TPN = DOUT/8 lanes per node. Softmax max/sum via subgroup shuffles (e is
// recomputed from L1-hot asrc each pass: no alpha array, no global RAW).
// Gather pass: each lane owns 8 features (16B bf16 load per edge); per-edge
// (w, src) broadcast from the owning lane via __shfl.
template <int DOUT>
__global__ void gather_fused(const int* __restrict__ off, const int* __restrict__ csr_src,
                             const float* __restrict__ asrc, const float* __restrict__ adst,
                             const unsigned short* __restrict__ hb,
                             const float* __restrict__ b, float* __restrict__ out, int N) {
    constexpr int TPN = DOUT / 8;
    int t = blockIdx.x * blockDim.x + threadIdx.x;
    int d = t / TPN;
    if (d >= N) return;
    int l = t % TPN;
    int p0 = off[d], p1 = off[d + 1];
    float ad = adst[d];

    float mx = -1e30f;
    for (int p = p0 + l; p < p1; p += TPN) {
        float e = asrc[csr_src[p]] + ad;
        e = e > 0.f ? e : 0.2f * e;              // leaky_relu(0.2)
        mx = fmaxf(mx, e);
    }
#pragma unroll
    for (int o = TPN / 2; o > 0; o >>= 1) mx = fmaxf(mx, __shfl_xor(mx, o, TPN));

    float sum = 0.f;
    for (int p = p0 + l; p < p1; p += TPN) {
        float e = asrc[csr_src[p]] + ad;
        e = e > 0.f ? e : 0.2f * e;
        sum += __expf(e - mx);
    }
#pragma unroll
    for (int o = TPN / 2; o > 0; o >>= 1) sum += __shfl_xor(sum, o, TPN);
    float inv = 1.f / sum;                        // self-loop guarantees sum > 0

    float acc[8];
#pragma unroll
    for (int i = 0; i < 8; ++i) acc[i] = 0.f;
    const int f0 = l * 8;

    for (int base = p0; base < p1; base += TPN) {
        int myp = base + l;
        float w = 0.f;
        int s = 0;
        if (myp < p1) {
            s = csr_src[myp];
            float e = asrc[s] + ad;
            e = e > 0.f ? e : 0.2f * e;
            w = __expf(e - mx) * inv;
        }
        int rem = min(TPN, p1 - base);
        for (int j = 0; j < rem; ++j) {
            float aj = __shfl(w, j, TPN);
            int sj = __shfl(s, j, TPN);
            const uint4 hv = *(const uint4*)(hb + (long)sj * DOUT + f0);
            acc[0] += aj * bf2f((unsigned short)(hv.x & 0xffff));
            acc[1] += aj * bf2f((unsigned short)(hv.x >> 16));
            acc[2] += aj * bf2f((unsigned short)(hv.y & 0xffff));
            acc[3] += aj * bf2f((unsigned short)(hv.y >> 16));
            acc[4] += aj * bf2f((unsigned short)(hv.z & 0xffff));
            acc[5] += aj * bf2f((unsigned short)(hv.z >> 16));
            acc[6] += aj * bf2f((unsigned short)(hv.w & 0xffff));
            acc[7] += aj * bf2f((unsigned short)(hv.w >> 16));
        }
    }

    float4 b0 = *(const float4*)(b + f0);
    float4 b1 = *(const float4*)(b + f0 + 4);
    float bb[8] = {b0.x, b0.y, b0.z, b0.w, b1.x, b1.y, b1.z, b1.w};
    float4 o0, o1;
    float* op = &o0.x;
#pragma unroll
    for (int i = 0; i < 8; ++i) {
        float v = acc[i] + bb[i];
        v = v > 0.f ? v : 0.01f * v;             // leaky_relu(0.01)
        ((i < 4) ? (&o0.x) : (&o1.x))[i & 3] = v;
    }
    (void)op;
    *(float4*)(out + (long)d * DOUT + f0) = o0;
    *(float4*)(out + (long)d * DOUT + f0 + 4) = o1;
}

// ---------------- BN statistics (read-only pass) -----------------------------
template <int DOUT>
__global__ void stats_k(const float* __restrict__ y, float* __restrict__ bnsum,
                        float* __restrict__ bnsq, int N) {
    __shared__ float ssum[DOUT];
    __shared__ float ssq[DOUT];
    for (int i = threadIdx.x; i < DOUT; i += blockDim.x) { ssum[i] = 0.f; ssq[i] = 0.f; }
    __syncthreads();
    int f = threadIdx.x % DOUT;
    float lsum = 0.f, lsq = 0.f;
    long total = (long)N * DOUT;
    long stride = (long)gridDim.x * blockDim.x;
    for (long t = (long)blockIdx.x * blockDim.x + threadIdx.x; t < total; t += stride) {
        float v = y[t];
        lsum += v; lsq += v * v;
    }
    atomicAdd(&ssum[f], lsum);
    atomicAdd(&ssq[f], lsq);
    __syncthreads();
    for (int i = threadIdx.x; i < DOUT; i += blockDim.x) {
        atomicAdd(&bnsum[i], ssum[i]);
        atomicAdd(&bnsq[i], ssq[i]);
    }
}

__global__ void bn_coef(const float* __restrict__ bnsum, const float* __restrict__ bnsq,
                        const float* __restrict__ g, const float* __restrict__ be,
                        float* __restrict__ coef, int DOUT, float invN) {
    int f = threadIdx.x;
    if (f >= DOUT) return;
    float mu = bnsum[f] * invN;
    float var = bnsq[f] * invN - mu * mu;        // biased variance (reference)
    float a = g[f] * rsqrtf(var + 1e-5f);
    coef[f] = a;
    coef[DOUT + f] = be[f] - mu * a;
}

template <int DOUT>
__global__ void bn_apply(float* __restrict__ y, const float* __restrict__ coef, long nq) {
    long t = (long)blockIdx.x * blockDim.x + threadIdx.x;
    if (t >= nq) return;
    int fq = (int)(t % (DOUT / 4)) * 4;
    float4 a = *(const float4*)(coef + fq);
    float4 c = *(const float4*)(coef + DOUT + fq);
    float4 v = *(float4*)(y + t * 4);
    v.x = v.x * a.x + c.x; v.y = v.y * a.y + c.y;
    v.z = v.z * a.z + c.z; v.w = v.w * a.w + c.w;
    *(float4*)(y + t * 4) = v;
}

// ---------------- pool over contiguous per-graph ranges (batch sorted) -------
__global__ void grange_k(const int* __restrict__ batch, int* __restrict__ gs,
                         int* __restrict__ ge, int N) {
    int n = blockIdx.x * blockDim.x + threadIdx.x;
    if (n >= N) return;
    int b = batch[n];
    atomicMin(&gs[b], n);
    atomicMax(&ge[b], n);
}

__global__ void pool_range_k(const float* __restrict__ h, const int* __restrict__ gs,
                             const int* __restrict__ ge, float* __restrict__ pooled) {
    int g = blockIdx.x;
    int f = threadIdx.x;                          // 64 threads
    int s0 = gs[g], s1 = ge[g];
    float acc = 0.f;
    if (s0 <= s1)
        for (int n = s0; n <= s1; ++n) acc += h[(long)n * 64 + f];
    pooled[(long)g * 64 + f] = acc;
}

// ---------------- MLP head ----------------------------------------------------
__global__ void head_k(const float* __restrict__ pooled, const float* __restrict__ Wf,
                       const float* __restrict__ bf, const float* __restrict__ Wc,
                       const float* __restrict__ bc, float* __restrict__ out) {
    int g = blockIdx.x;
    int t = threadIdx.x;                          // 64 threads
    __shared__ float p[64];
    __shared__ float z[32];
    p[t] = pooled[(long)g * 64 + t];
    __syncthreads();
    if (t < 32) {
        float acc = bf[t];
#pragma unroll
        for (int f = 0; f < 64; ++f) acc += p[f] * Wf[f * 32 + t];
        z[t] = acc > 0.f ? acc : 0.01f * acc;
    }
    __syncthreads();
    if (t < 8) {
        float acc = bc[t];
#pragma unroll
        for (int o = 0; o < 32; ++o) acc += z[o] * Wc[o * 8 + t];
        out[(long)g * 8 + t] = 1.f / (1.f + __expf(-acc));
    }
}

extern "C" void kernel_launch(void* const* d_in, const int* in_sizes, int n_in,
                              void* d_out, int out_size, void* d_ws, size_t ws_size,
                              hipStream_t stream) {
    const float* x   = (const float*)d_in[0];
    const int* ei    = (const int*)d_in[1];
    const int* batch = (const int*)d_in[2];
    const int N  = in_sizes[2];
    const int E  = in_sizes[1] / 2;
    const int ET = E + N;
    const int G  = out_size / 8;
    const int* src = ei;
    const int* dst = ei + E;

    const float *W[4], *as_[4], *ad_[4], *bb[4], *gg[4], *be_[4];
    for (int i = 0; i < 4; ++i) {
        W[i]   = (const float*)d_in[3 + 6 * i];
        as_[i] = (const float*)d_in[4 + 6 * i];
        ad_[i] = (const float*)d_in[5 + 6 * i];
        bb[i]  = (const float*)d_in[6 + 6 * i];
        gg[i]  = (const float*)d_in[7 + 6 * i];
        be_[i] = (const float*)d_in[8 + 6 * i];
    }
    const float* Wf = (const float*)d_in[27];
    const float* bf = (const float*)d_in[28];
    const float* Wc = (const float*)d_in[29];
    const float* bc = (const float*)d_in[30];

    float* ws = (float*)d_ws;
    long off_ = 0;
    auto alloc = [&](long nelem) { float* p = ws + off_; off_ += (nelem + 3) & ~3L; return p; };
    unsigned short* hb = (unsigned short*)alloc((long)N * 64);  // h in bf16 (max 128 feat)
    float* B       = alloc((long)N * 128);   // layer output / next input (fp32)
    float* asrc    = alloc(N);
    float* adst    = alloc(N);
    float* bnstats = alloc(256);             // bnsum(128) + bnsq(128)
    float* coef    = alloc(256);
    float* pooled  = alloc((long)G * 64);
    int* deg     = (int*)alloc(N);
    int* off     = (int*)alloc(N + 1);
    int* bsum    = (int*)alloc(BLK);
    int* fillc   = (int*)alloc(N);
    int* csr_src = (int*)alloc(ET);
    int* gs      = (int*)alloc(G);
    int* ge      = (int*)alloc(G);
    float* bnsum = bnstats;
    float* bnsq  = bnstats + 128;
    (void)ws_size; (void)n_in;

    const int nblk = cdiv(N, BLK);           // 196 <= 256

    // ---- CSR build (per call; graph static across layers) ----
    hipMemsetAsync(deg, 0, N * sizeof(int), stream);
    hipMemsetAsync(fillc, 0, N * sizeof(int), stream);
    hist_k<<<cdiv(ET, BLK), BLK, 0, stream>>>(dst, deg, ET, E);
    scan_block_k<<<nblk, BLK, 0, stream>>>(deg, off, bsum, N);
    scan_sums_k<<<1, BLK, 0, stream>>>(bsum, nblk, off + N, ET);
    scan_add_k<<<nblk, BLK, 0, stream>>>(off, bsum, N);
    fill_k<<<cdiv(ET, BLK), BLK, 0, stream>>>(src, dst, off, fillc, csr_src, ET, E);

    // ---- per-graph node ranges for pooling ----
    hipMemsetAsync(gs, 0x7f, G * sizeof(int), stream);
    hipMemsetAsync(ge, 0xff, G * sizeof(int), stream);
    grange_k<<<cdiv(N, BLK), BLK, 0, stream>>>(batch, gs, ge, N);

#define LAYER(i, DIN, DOUT, INPTR)                                                        \
    do {                                                                                  \
        hipMemsetAsync(bnstats, 0, 256 * sizeof(float), stream);                          \
        gemm_attn<DIN, DOUT><<<cdiv((long)N * (DOUT / 4), BLK), BLK, 0, stream>>>(        \
            INPTR, W[i], as_[i], ad_[i], hb, asrc, adst, N);                              \
        gather_fused<DOUT><<<cdiv((long)N * (DOUT / 8), BLK), BLK, 0, stream>>>(          \
            off, csr_src, asrc, adst, hb, bb[i], B, N);                                   \
        stats_k<DOUT><<<512, BLK, 0, stream>>>(B, bnsum, bnsq, N);                        \
        bn_coef<<<1, 128, 0, stream>>>(bnsum, bnsq, gg[i], be_[i], coef, DOUT, 1.f / N);  \
        bn_apply<DOUT><<<cdiv((long)N * DOUT / 4, BLK), BLK, 0, stream>>>(B, coef,        \
                                                                (long)N * DOUT / 4);      \
    } while (0)

    LAYER(0, 128, 32, x);
    LAYER(1, 32, 64, B);
    LAYER(2, 64, 128, B);
    LAYER(3, 128, 64, B);
#undef LAYER

    pool_range_k<<<G, 64, 0, stream>>>(B, gs, ge, pooled);
    head_k<<<G, 64, 0, stream>>>(pooled, Wf, bf, Wc, bc, (float*)d_out);
}

// Round 4
// 675.051 us; speedup vs baseline: 6.0260x; 1.0486x over previous
//
#include <hip/hip_runtime.h>
#include <math.h>

constexpr int BLK = 256;

static inline int cdiv(long a, long b) { return (int)((a + b - 1) / b); }

typedef __attribute__((ext_vector_type(8))) short short8;
typedef __attribute__((ext_vector_type(4))) float floatx4;

// ---------------- bf16 helpers (RNE) -----------------------------------------
__device__ __forceinline__ unsigned short f2bf(float f) {
    unsigned u = __float_as_uint(f);
    unsigned r = u + 0x7fffu + ((u >> 16) & 1u);
    return (unsigned short)(r >> 16);
}
__device__ __forceinline__ float bf2f(unsigned short s) {
    return __uint_as_float(((unsigned)s) << 16);
}

// ---------------- cast fp32 -> bf16 ------------------------------------------
__global__ void cast_bf16_k(const float* __restrict__ x, unsigned short* __restrict__ o,
                            long n4) {
    long t = (long)blockIdx.x * blockDim.x + threadIdx.x;
    if (t >= n4) return;
    float4 v = *(const float4*)(x + t * 4);
    ushort4 u = {f2bf(v.x), f2bf(v.y), f2bf(v.z), f2bf(v.w)};
    *(ushort4*)(o + t * 4) = u;
}

// ---------------- per-layer prep: fold BN into W -----------------------------
// Wscaled[k][f] = a[k]*W[k][f] (bf16), bias_add[f] = sum_k c[k]W[k][f],
// was[k] = a[k]*(W[k,:]@a_s), wad likewise, bdots = bias_add @ {a_s, a_d}.
// coef == nullptr -> a=1, c=0 (layer 0).
__global__ void prep_k(const float* __restrict__ W, const float* __restrict__ a_s,
                       const float* __restrict__ a_d, const float* __restrict__ coef,
                       unsigned short* __restrict__ Wb, float* __restrict__ bias_add,
                       float* __restrict__ was, float* __restrict__ wad,
                       float* __restrict__ bdots, int K, int Nout) {
    int tid = threadIdx.x;
    for (int idx = tid; idx < K * Nout; idx += BLK) {
        int k = idx / Nout;
        float a = coef ? coef[k] : 1.f;
        Wb[idx] = f2bf(a * W[idx]);
    }
    for (int f = tid; f < Nout; f += BLK) {
        float s = 0.f;
        for (int k = 0; k < K; ++k) {
            float c = coef ? coef[128 + k] : 0.f;
            s += c * W[k * Nout + f];
        }
        bias_add[f] = s;
    }
    for (int k = tid; k < K; k += BLK) {
        float a = coef ? coef[k] : 1.f;
        float s1 = 0.f, s2 = 0.f;
        for (int f = 0; f < Nout; ++f) {
            float w = W[k * Nout + f];
            s1 += w * a_s[f];
            s2 += w * a_d[f];
        }
        was[k] = a * s1;
        wad[k] = a * s2;
    }
    __syncthreads();
    if (tid == 0) {
        float s1 = 0.f, s2 = 0.f;
        for (int f = 0; f < Nout; ++f) {
            s1 += bias_add[f] * a_s[f];
            s2 += bias_add[f] * a_d[f];
        }
        bdots[0] = s1;
        bdots[1] = s2;
    }
}

// ---------------- MFMA GEMM: hb = h2 @ Wb + bias_add, + attention dots -------
// 16x16x32 bf16 MFMA. A: row=lane&15, k=quad*8+j. B: k=quad*8+j, col=lane&15.
// C/D: col=lane&15, row=quad*4+reg. Block = 4 waves x 2 row-tiles x 16 rows,
// grid.y = col-tile. col-tile 0 also computes asrc/adst from A frags via
// folded vectors was/wad (quad-reduce over shuffles, no atomics).
template <int K, int NOUT>
__launch_bounds__(256)
__global__ void gemm_mfma(const unsigned short* __restrict__ h2,
                          const unsigned short* __restrict__ Wb,
                          const float* __restrict__ bias_add,
                          const float* __restrict__ was, const float* __restrict__ wad,
                          const float* __restrict__ bdots,
                          unsigned short* __restrict__ hb,
                          float* __restrict__ asrc, float* __restrict__ adst, int N) {
    constexpr int KF = K / 32;
    int wave = threadIdx.x >> 6;
    int lane = threadIdx.x & 63;
    int quad = lane >> 4;
    int r16 = lane & 15;
    int col = blockIdx.y * 16 + r16;

    short8 bfr[KF];
#pragma unroll
    for (int kk = 0; kk < KF; ++kk) {
        short8 b;
#pragma unroll
        for (int j = 0; j < 8; ++j)
            b[j] = (short)Wb[(kk * 32 + quad * 8 + j) * NOUT + col];
        bfr[kk] = b;
    }
    const bool dodots = (blockIdx.y == 0);
    float biasv = bias_add[col];
    int blockbase = blockIdx.x * 128;

#pragma unroll
    for (int rt = 0; rt < 2; ++rt) {
        int tilebase = blockbase + wave * 32 + rt * 16;
        if (tilebase >= N) break;                       // wave-uniform
        int arow = tilebase + r16;
        if (arow > N - 1) arow = N - 1;
        short8 afr[KF];
#pragma unroll
        for (int kk = 0; kk < KF; ++kk)
            afr[kk] = *(const short8*)(h2 + (long)arow * K + kk * 32 + quad * 8);
        floatx4 acc = {0.f, 0.f, 0.f, 0.f};
#pragma unroll
        for (int kk = 0; kk < KF; ++kk)
            acc = __builtin_amdgcn_mfma_f32_16x16x32_bf16(afr[kk], bfr[kk], acc, 0, 0, 0);
#pragma unroll
        for (int rr = 0; rr < 4; ++rr) {
            int srow = tilebase + quad * 4 + rr;
            if (srow < N) hb[(long)srow * NOUT + col] = f2bf(acc[rr] + biasv);
        }
        if (dodots) {
            float ds = 0.f, dd = 0.f;
#pragma unroll
            for (int kk = 0; kk < KF; ++kk) {
                int kb = kk * 32 + quad * 8;
#pragma unroll
                for (int j = 0; j < 8; ++j) {
                    float av = bf2f((unsigned short)afr[kk][j]);
                    ds += av * was[kb + j];
                    dd += av * wad[kb + j];
                }
            }
            ds += __shfl_xor(ds, 16, 64); ds += __shfl_xor(ds, 32, 64);
            dd += __shfl_xor(dd, 16, 64); dd += __shfl_xor(dd, 32, 64);
            int drow = tilebase + r16;
            if (quad == 0 && drow < N) {
                asrc[drow] = ds + bdots[0];
                adst[drow] = dd + bdots[1];
            }
        }
    }
}

// ---------------- CSR build: histogram -> exclusive scan -> fill -------------
__global__ void hist_k(const int* __restrict__ dst, int* __restrict__ deg, int ET, int E) {
    int j = blockIdx.x * blockDim.x + threadIdx.x;
    if (j >= ET) return;
    int d = (j < E) ? dst[j] : (j - E);
    atomicAdd(&deg[d], 1);
}

__global__ void scan_block_k(const int* __restrict__ deg, int* __restrict__ off,
                             int* __restrict__ bsum, int N) {
    __shared__ int s[BLK];
    int i = blockIdx.x * BLK + threadIdx.x;
    int v = (i < N) ? deg[i] : 0;
    s[threadIdx.x] = v;
    __syncthreads();
    for (int o = 1; o < BLK; o <<= 1) {
        int t = (threadIdx.x >= o) ? s[threadIdx.x - o] : 0;
        __syncthreads();
        s[threadIdx.x] += t;
        __syncthreads();
    }
    if (i < N) off[i] = s[threadIdx.x] - v;
    if (threadIdx.x == BLK - 1) bsum[blockIdx.x] = s[BLK - 1];
}

__global__ void scan_sums_k(int* __restrict__ bsum, int nblk, int* __restrict__ off_end,
                            int total) {
    __shared__ int s[BLK];
    int v = (threadIdx.x < nblk) ? bsum[threadIdx.x] : 0;
    s[threadIdx.x] = v;
    __syncthreads();
    for (int o = 1; o < BLK; o <<= 1) {
        int t = (threadIdx.x >= o) ? s[threadIdx.x - o] : 0;
        __syncthreads();
        s[threadIdx.x] += t;
        __syncthreads();
    }
    if (threadIdx.x < nblk) bsum[threadIdx.x] = s[threadIdx.x] - v;
    if (threadIdx.x == 0) *off_end = total;
}

__global__ void scan_add_k(int* __restrict__ off, const int* __restrict__ bsum, int N) {
    int i = blockIdx.x * BLK + threadIdx.x;
    if (i < N) off[i] += bsum[blockIdx.x];
}

__global__ void fill_k(const int* __restrict__ src, const int* __restrict__ dst,
                       const int* __restrict__ off, int* __restrict__ fill,
                       int* __restrict__ csr_src, int ET, int E) {
    int j = blockIdx.x * blockDim.x + threadIdx.x;
    if (j >= ET) return;
    int d = (j < E) ? dst[j] : (j - E);
    int s = (j < E) ? src[j] : (j - E);
    int pos = off[d] + atomicAdd(&fill[d], 1);
    csr_src[pos] = s;
}

// ---------------- fused softmax + gather + bias + leaky(0.01), bf16 out ------
template <int DOUT>
__global__ void gather_fused(const int* __restrict__ off, const int* __restrict__ csr_src,
                             const float* __restrict__ asrc, const float* __restrict__ adst,
                             const unsigned short* __restrict__ hb,
                             const float* __restrict__ b,
                             unsigned short* __restrict__ out, int N) {
    constexpr int TPN = DOUT / 8;
    int t = blockIdx.x * blockDim.x + threadIdx.x;
    int d = t / TPN;
    if (d >= N) return;
    int l = t % TPN;
    int p0 = off[d], p1 = off[d + 1];
    float ad = adst[d];

    float mx = -1e30f;
    for (int p = p0 + l; p < p1; p += TPN) {
        float e = asrc[csr_src[p]] + ad;
        e = e > 0.f ? e : 0.2f * e;
        mx = fmaxf(mx, e);
    }
#pragma unroll
    for (int o = TPN / 2; o > 0; o >>= 1) mx = fmaxf(mx, __shfl_xor(mx, o, TPN));

    float sum = 0.f;
    for (int p = p0 + l; p < p1; p += TPN) {
        float e = asrc[csr_src[p]] + ad;
        e = e > 0.f ? e : 0.2f * e;
        sum += __expf(e - mx);
    }
#pragma unroll
    for (int o = TPN / 2; o > 0; o >>= 1) sum += __shfl_xor(sum, o, TPN);
    float inv = 1.f / sum;

    float acc[8];
#pragma unroll
    for (int i = 0; i < 8; ++i) acc[i] = 0.f;
    const int f0 = l * 8;

    for (int base = p0; base < p1; base += TPN) {
        int myp = base + l;
        float w = 0.f;
        int s = 0;
        if (myp < p1) {
            s = csr_src[myp];
            float e = asrc[s] + ad;
            e = e > 0.f ? e : 0.2f * e;
            w = __expf(e - mx) * inv;
        }
        int rem = min(TPN, p1 - base);
        for (int j = 0; j < rem; ++j) {
            float aj = __shfl(w, j, TPN);
            int sj = __shfl(s, j, TPN);
            const uint4 hv = *(const uint4*)(hb + (long)sj * DOUT + f0);
            acc[0] += aj * bf2f((unsigned short)(hv.x & 0xffff));
            acc[1] += aj * bf2f((unsigned short)(hv.x >> 16));
            acc[2] += aj * bf2f((unsigned short)(hv.y & 0xffff));
            acc[3] += aj * bf2f((unsigned short)(hv.y >> 16));
            acc[4] += aj * bf2f((unsigned short)(hv.z & 0xffff));
            acc[5] += aj * bf2f((unsigned short)(hv.z >> 16));
            acc[6] += aj * bf2f((unsigned short)(hv.w & 0xffff));
            acc[7] += aj * bf2f((unsigned short)(hv.w >> 16));
        }
    }

    float4 b0 = *(const float4*)(b + f0);
    float4 b1 = *(const float4*)(b + f0 + 4);
    float bb[8] = {b0.x, b0.y, b0.z, b0.w, b1.x, b1.y, b1.z, b1.w};
    ushort4 o0, o1;
#pragma unroll
    for (int i = 0; i < 8; ++i) {
        float v = acc[i] + bb[i];
        v = v > 0.f ? v : 0.01f * v;
        unsigned short hv = f2bf(v);
        if (i < 4) ((unsigned short*)&o0)[i] = hv;
        else       ((unsigned short*)&o1)[i - 4] = hv;
    }
    *(ushort4*)(out + (long)d * DOUT + f0) = o0;
    *(ushort4*)(out + (long)d * DOUT + f0 + 4) = o1;
}

// ---------------- BN statistics over bf16 activations ------------------------
template <int DOUT>
__global__ void stats_k(const unsigned short* __restrict__ y, float* __restrict__ bnsum,
                        float* __restrict__ bnsq, int N) {
    constexpr int QPR = DOUT / 8;
    __shared__ float ssum[DOUT];
    __shared__ float ssq[DOUT];
    for (int i = threadIdx.x; i < DOUT; i += blockDim.x) { ssum[i] = 0.f; ssq[i] = 0.f; }
    __syncthreads();
    long total = (long)N * QPR;
    long stride = (long)gridDim.x * blockDim.x;     // 512*256, multiple of QPR
    long t0 = (long)blockIdx.x * blockDim.x + threadIdx.x;
    int f0 = (int)(t0 % QPR) * 8;
    float ls[8], lq[8];
#pragma unroll
    for (int i = 0; i < 8; ++i) { ls[i] = 0.f; lq[i] = 0.f; }
    for (long t = t0; t < total; t += stride) {
        uint4 hv = *(const uint4*)(y + t * 8);
        unsigned vv[4] = {hv.x, hv.y, hv.z, hv.w};
#pragma unroll
        for (int q = 0; q < 4; ++q) {
            float v0 = bf2f((unsigned short)(vv[q] & 0xffff));
            float v1 = bf2f((unsigned short)(vv[q] >> 16));
            ls[2 * q] += v0;     lq[2 * q] += v0 * v0;
            ls[2 * q + 1] += v1; lq[2 * q + 1] += v1 * v1;
        }
    }
#pragma unroll
    for (int i = 0; i < 8; ++i) {
        atomicAdd(&ssum[f0 + i], ls[i]);
        atomicAdd(&ssq[f0 + i], lq[i]);
    }
    __syncthreads();
    for (int i = threadIdx.x; i < DOUT; i += blockDim.x) {
        atomicAdd(&bnsum[i], ssum[i]);
        atomicAdd(&bnsq[i], ssq[i]);
    }
}

__global__ void bn_coef(const float* __restrict__ bnsum, const float* __restrict__ bnsq,
                        const float* __restrict__ g, const float* __restrict__ be,
                        float* __restrict__ coef, int DOUT, float invN) {
    int f = threadIdx.x;
    if (f >= DOUT) return;
    float mu = bnsum[f] * invN;
    float var = bnsq[f] * invN - mu * mu;
    float a = g[f] * rsqrtf(var + 1e-5f);
    coef[f] = a;
    coef[128 + f] = be[f] - mu * a;
}

// ---------------- pool with folded final BN ----------------------------------
__global__ void grange_k(const int* __restrict__ batch, int* __restrict__ gs,
                         int* __restrict__ ge, int N) {
    int n = blockIdx.x * blockDim.x + threadIdx.x;
    if (n >= N) return;
    int b = batch[n];
    atomicMin(&gs[b], n);
    atomicMax(&ge[b], n);
}

__global__ void pool_bn_k(const unsigned short* __restrict__ h, const int* __restrict__ gs,
                          const int* __restrict__ ge, const float* __restrict__ coef,
                          float* __restrict__ pooled) {
    int g = blockIdx.x;
    int f = threadIdx.x;                          // 64 threads
    int s0 = gs[g], s1 = ge[g];
    float acc = 0.f;
    float cnt = 0.f;
    if (s0 <= s1) {
        cnt = (float)(s1 - s0 + 1);
        for (int n = s0; n <= s1; ++n) acc += bf2f(h[(long)n * 64 + f]);
    }
    pooled[(long)g * 64 + f] = coef[f] * acc + cnt * coef[128 + f];
}

// ---------------- MLP head ----------------------------------------------------
__global__ void head_k(const float* __restrict__ pooled, const float* __restrict__ Wf,
                       const float* __restrict__ bf, const float* __restrict__ Wc,
                       const float* __restrict__ bc, float* __restrict__ out) {
    int g = blockIdx.x;
    int t = threadIdx.x;                          // 64 threads
    __shared__ float p[64];
    __shared__ float z[32];
    p[t] = pooled[(long)g * 64 + t];
    __syncthreads();
    if (t < 32) {
        float acc = bf[t];
#pragma unroll
        for (int f = 0; f < 64; ++f) acc += p[f] * Wf[f * 32 + t];
        z[t] = acc > 0.f ? acc : 0.01f * acc;
    }
    __syncthreads();
    if (t < 8) {
        float acc = bc[t];
#pragma unroll
        for (int o = 0; o < 32; ++o) acc += z[o] * Wc[o * 8 + t];
        out[(long)g * 8 + t] = 1.f / (1.f + __expf(-acc));
    }
}

extern "C" void kernel_launch(void* const* d_in, const int* in_sizes, int n_in,
                              void* d_out, int out_size, void* d_ws, size_t ws_size,
                              hipStream_t stream) {
    const float* x   = (const float*)d_in[0];
    const int* ei    = (const int*)d_in[1];
    const int* batch = (const int*)d_in[2];
    const int N  = in_sizes[2];
    const int E  = in_sizes[1] / 2;
    const int ET = E + N;
    const int G  = out_size / 8;
    const int* src = ei;
    const int* dst = ei + E;

    const float *W[4], *as_[4], *ad_[4], *bb[4], *gg[4], *be_[4];
    for (int i = 0; i < 4; ++i) {
        W[i]   = (const float*)d_in[3 + 6 * i];
        as_[i] = (const float*)d_in[4 + 6 * i];
        ad_[i] = (const float*)d_in[5 + 6 * i];
        bb[i]  = (const float*)d_in[6 + 6 * i];
        gg[i]  = (const float*)d_in[7 + 6 * i];
        be_[i] = (const float*)d_in[8 + 6 * i];
    }
    const float* Wf = (const float*)d_in[27];
    const float* bf = (const float*)d_in[28];
    const float* Wc = (const float*)d_in[29];
    const float* bc = (const float*)d_in[30];

    float* ws = (float*)d_ws;
    long off_ = 0;
    auto alloc = [&](long nelem) { float* p = ws + off_; off_ += (nelem + 3) & ~3L; return p; };
    unsigned short* h2a = (unsigned short*)alloc((long)N * 64);  // N x 128 bf16
    unsigned short* h2b = (unsigned short*)alloc((long)N * 64);
    unsigned short* hb  = (unsigned short*)alloc((long)N * 64);
    unsigned short* Wb  = (unsigned short*)alloc(8192);          // 128x128 bf16
    float* bias_add = alloc(128);
    float* was      = alloc(128);
    float* wad      = alloc(128);
    float* bdots    = alloc(4);
    float* asrc     = alloc(N);
    float* adst     = alloc(N);
    float* bnstats  = alloc(256);
    float* coef     = alloc(256);
    float* pooled   = alloc((long)G * 64);
    int* deg     = (int*)alloc(N);
    int* off     = (int*)alloc(N + 1);
    int* bsum    = (int*)alloc(BLK);
    int* fillc   = (int*)alloc(N);
    int* csr_src = (int*)alloc(ET);
    int* gs      = (int*)alloc(G);
    int* ge      = (int*)alloc(G);
    float* bnsum = bnstats;
    float* bnsq  = bnstats + 128;
    (void)ws_size; (void)n_in;

    const int nblk = cdiv(N, BLK);

    // ---- input cast + CSR build + graph ranges ----
    cast_bf16_k<<<cdiv((long)N * 32, BLK), BLK, 0, stream>>>(x, h2a, (long)N * 32);
    hipMemsetAsync(deg, 0, N * sizeof(int), stream);
    hipMemsetAsync(fillc, 0, N * sizeof(int), stream);
    hist_k<<<cdiv(ET, BLK), BLK, 0, stream>>>(dst, deg, ET, E);
    scan_block_k<<<nblk, BLK, 0, stream>>>(deg, off, bsum, N);
    scan_sums_k<<<1, BLK, 0, stream>>>(bsum, nblk, off + N, ET);
    scan_add_k<<<nblk, BLK, 0, stream>>>(off, bsum, N);
    fill_k<<<cdiv(ET, BLK), BLK, 0, stream>>>(src, dst, off, fillc, csr_src, ET, E);
    hipMemsetAsync(gs, 0x7f, G * sizeof(int), stream);
    hipMemsetAsync(ge, 0xff, G * sizeof(int), stream);
    grange_k<<<cdiv(N, BLK), BLK, 0, stream>>>(batch, gs, ge, N);

#define LAYER(i, DIN, DOUT, INP, OUTP, CF)                                                \
    do {                                                                                  \
        prep_k<<<1, BLK, 0, stream>>>(W[i], as_[i], ad_[i], CF, Wb, bias_add, was, wad,   \
                                      bdots, DIN, DOUT);                                  \
        gemm_mfma<DIN, DOUT><<<dim3(cdiv(N, 128), DOUT / 16), 256, 0, stream>>>(          \
            INP, Wb, bias_add, was, wad, bdots, hb, asrc, adst, N);                       \
        gather_fused<DOUT><<<cdiv((long)N * (DOUT / 8), BLK), BLK, 0, stream>>>(          \
            off, csr_src, asrc, adst, hb, bb[i], OUTP, N);                                \
        hipMemsetAsync(bnstats, 0, 256 * sizeof(float), stream);                          \
        stats_k<DOUT><<<512, BLK, 0, stream>>>(OUTP, bnsum, bnsq, N);                     \
        bn_coef<<<1, 128, 0, stream>>>(bnsum, bnsq, gg[i], be_[i], coef, DOUT, 1.f / N);  \
    } while (0)

    LAYER(0, 128, 32, h2a, h2b, (const float*)nullptr);
    LAYER(1, 32, 64, h2b, h2a, coef);
    LAYER(2, 64, 128, h2a, h2b, coef);
    LAYER(3, 128, 64, h2b, h2a, coef);
#undef LAYER

    pool_bn_k<<<G, 64, 0, stream>>>(h2a, gs, ge, coef, pooled);
    head_k<<<G, 64, 0, stream>>>(pooled, Wf, bf, Wc, bc, (float*)d_out);
}

// Round 5
// 460.772 us; speedup vs baseline: 8.8283x; 1.4650x over previous
//
#include <hip/hip_runtime.h>
#include <math.h>

constexpr int BLK = 256;
constexpr int NBLKA = 256;     // phase-A blocks for edge bucketing

static inline int cdiv(long a, long b) { return (int)((a + b - 1) / b); }

typedef __attribute__((ext_vector_type(8))) short short8;
typedef __attribute__((ext_vector_type(4))) float floatx4;

// ---------------- bf16 helpers (RNE) -----------------------------------------
__device__ __forceinline__ unsigned short f2bf(float f) {
    unsigned u = __float_as_uint(f);
    unsigned r = u + 0x7fffu + ((u >> 16) & 1u);
    return (unsigned short)(r >> 16);
}
__device__ __forceinline__ float bf2f(unsigned short s) {
    return __uint_as_float(((unsigned)s) << 16);
}

// ---------------- cast fp32 -> bf16 ------------------------------------------
__global__ void cast_bf16_k(const float* __restrict__ x, unsigned short* __restrict__ o,
                            long n4) {
    long t = (long)blockIdx.x * blockDim.x + threadIdx.x;
    if (t >= n4) return;
    float4 v = *(const float4*)(x + t * 4);
    ushort4 u = {f2bf(v.x), f2bf(v.y), f2bf(v.z), f2bf(v.w)};
    *(ushort4*)(o + t * 4) = u;
}

// ============== CSR build via 2-phase bucket sort (NO global atomics) ========
// Bucket b covers nodes [b*256, b*256+256). histg layout: [z*nbkt + b].

// A1: per-block histogram of dst>>8 over its edge chunk.
__global__ void histA_k(const int* __restrict__ dst, int* __restrict__ histg,
                        int E, int nbkt, int chunk) {
    __shared__ int h[256];
    int tid = threadIdx.x, z = blockIdx.x;
    h[tid] = 0;
    __syncthreads();
    int e0 = z * chunk, e1 = min(E, e0 + chunk);
    for (int e = e0 + tid; e < e1; e += BLK) atomicAdd(&h[dst[e] >> 8], 1);
    __syncthreads();
    if (tid < nbkt) histg[tid * 0 + z * nbkt + tid] = h[tid];
}

// A2: bucket totals + exclusive scan -> bucket_base; also init gs/ge.
__global__ void bucket_scan_k(const int* __restrict__ histg, int* __restrict__ bucket_base,
                              int nbkt, int E, int* __restrict__ gs, int* __restrict__ ge,
                              int G) {
    __shared__ int s[BLK];
    int t = threadIdx.x;
    int v = 0;
    if (t < nbkt)
        for (int z = 0; z < NBLKA; ++z) v += histg[z * nbkt + t];
    s[t] = v;
    __syncthreads();
    for (int o = 1; o < BLK; o <<= 1) {
        int tv = (t >= o) ? s[t - o] : 0;
        __syncthreads();
        s[t] += tv;
        __syncthreads();
    }
    if (t < nbkt) bucket_base[t] = s[t] - v;
    if (t == 0) bucket_base[nbkt] = E;
    for (int i = t; i < G; i += BLK) { gs[i] = 0x7fffffff; ge[i] = -1; }
}

// A3: per-bucket scan over phase-A blocks -> per-(bucket,block) base offsets.
__global__ void blk_scan_k(int* __restrict__ histg, const int* __restrict__ bucket_base,
                           int nbkt) {
    __shared__ int s[BLK];
    int t = threadIdx.x, b = blockIdx.x;
    int v = histg[t * nbkt + b];
    s[t] = v;
    __syncthreads();
    for (int o = 1; o < BLK; o <<= 1) {
        int tv = (t >= o) ? s[t - o] : 0;
        __syncthreads();
        s[t] += tv;
        __syncthreads();
    }
    histg[t * nbkt + b] = bucket_base[b] + s[t] - v;
}

// A4: scatter edges into bucket-ordered packed array (LDS cursors only).
__global__ void scatterA_k(const int* __restrict__ src, const int* __restrict__ dst,
                           const int* __restrict__ histg, unsigned* __restrict__ ebkt,
                           int E, int nbkt, int chunk) {
    __shared__ int cur[256];
    int tid = threadIdx.x, z = blockIdx.x;
    if (tid < nbkt) cur[tid] = histg[z * nbkt + tid];
    __syncthreads();
    int e0 = z * chunk, e1 = min(E, e0 + chunk);
    for (int e = e0 + tid; e < e1; e += BLK) {
        int d = dst[e];
        int b = d >> 8;
        int pos = atomicAdd(&cur[b], 1);
        ebkt[pos] = ((unsigned)(d & 255) << 16) | (unsigned)src[e];
    }
}

// B: per-bucket CSR finalize: degrees (LDS), scan, self-loop, fill (ushort src).
__global__ void csrB_k(const unsigned* __restrict__ ebkt, const int* __restrict__ bucket_base,
                       int* __restrict__ off, unsigned short* __restrict__ csr,
                       int N, int E, int nbkt) {
    __shared__ int dg[256];
    __shared__ int sc[256];
    int t = threadIdx.x, b = blockIdx.x;
    int n0 = b << 8;
    int cnt = min(256, N - n0);
    dg[t] = (t < cnt) ? 1 : 0;                     // self-loop
    __syncthreads();
    int e0 = bucket_base[b], e1 = bucket_base[b + 1];
    for (int e = e0 + t; e < e1; e += BLK) atomicAdd(&dg[ebkt[e] >> 16], 1);
    __syncthreads();
    int d = dg[t];
    sc[t] = d;
    __syncthreads();
    for (int o = 1; o < BLK; o <<= 1) {
        int tv = (t >= o) ? sc[t - o] : 0;
        __syncthreads();
        sc[t] += tv;
        __syncthreads();
    }
    int loff = sc[t] - d;                          // exclusive
    int csrbase = e0 + n0;                         // n0 self-loops precede bucket
    if (t < cnt) {
        off[n0 + t] = csrbase + loff;
        csr[csrbase + loff] = (unsigned short)(n0 + t);   // self-loop slot
        dg[t] = loff + 1;                          // cursor
    }
    if (b == nbkt - 1 && t == 0) off[N] = E + N;
    __syncthreads();
    for (int e = e0 + t; e < e1; e += BLK) {
        unsigned w = ebkt[e];
        int pos = atomicAdd(&dg[w >> 16], 1);
        csr[csrbase + pos] = (unsigned short)(w & 0xffff);
    }
}

// ---------------- per-graph node ranges (batch sorted, boundary detect) ------
__global__ void grange2_k(const int* __restrict__ batch, int* __restrict__ gs,
                          int* __restrict__ ge, int N) {
    int n = blockIdx.x * blockDim.x + threadIdx.x;
    if (n >= N) return;
    int b = batch[n];
    if (n == 0) gs[b] = 0;
    else {
        int pb = batch[n - 1];
        if (pb != b) { gs[b] = n; ge[pb] = n - 1; }
    }
    if (n == N - 1) ge[b] = N - 1;
}

// ---------------- per-layer prep: fold prev-layer BN + this layer's W --------
// coef a,c from prev layer's bn stats (bnst==nullptr -> identity).
// Wb[k][f]=a[k]W[k][f] bf16; bias_add[f]=sum_k c[k]W[k][f];
// was[k]=a[k](W[k,:]@a_s); wad likewise; bdots = bias_add @ {a_s,a_d}.
__global__ void prep_k(const float* __restrict__ W, const float* __restrict__ a_s,
                       const float* __restrict__ a_d, const float* __restrict__ bnst,
                       const float* __restrict__ g_prev, const float* __restrict__ be_prev,
                       float invN, unsigned short* __restrict__ Wb,
                       float* __restrict__ bias_add, float* __restrict__ was,
                       float* __restrict__ wad, float* __restrict__ bdots, int K, int Nout) {
    __shared__ float ca[128], cc[128], lb[128];
    int tid = threadIdx.x;
    if (tid < K) {
        float a = 1.f, c = 0.f;
        if (bnst) {
            float mu = bnst[tid] * invN;
            float var = bnst[128 + tid] * invN - mu * mu;
            a = g_prev[tid] * rsqrtf(var + 1e-5f);
            c = be_prev[tid] - mu * a;
        }
        ca[tid] = a; cc[tid] = c;
    }
    __syncthreads();
    for (int idx = tid; idx < K * Nout; idx += BLK) {
        int k = idx / Nout;
        Wb[idx] = f2bf(ca[k] * W[idx]);
    }
    for (int f = tid; f < Nout; f += BLK) {
        float s = 0.f;
        for (int k = 0; k < K; ++k) s += cc[k] * W[k * Nout + f];
        bias_add[f] = s;
        lb[f] = s;
    }
    for (int k = tid; k < K; k += BLK) {
        float s1 = 0.f, s2 = 0.f;
        for (int f = 0; f < Nout; ++f) {
            float w = W[k * Nout + f];
            s1 += w * a_s[f];
            s2 += w * a_d[f];
        }
        was[k] = ca[k] * s1;
        wad[k] = ca[k] * s2;
    }
    __syncthreads();
    if (tid == 0) {
        float s1 = 0.f, s2 = 0.f;
        for (int f = 0; f < Nout; ++f) {
            s1 += lb[f] * a_s[f];
            s2 += lb[f] * a_d[f];
        }
        bdots[0] = s1;
        bdots[1] = s2;
    }
}

// ---------------- MFMA GEMM: hb = h2 @ Wb + bias_add, + attention dots -------
template <int K, int NOUT>
__launch_bounds__(256)
__global__ void gemm_mfma(const unsigned short* __restrict__ h2,
                          const unsigned short* __restrict__ Wb,
                          const float* __restrict__ bias_add,
                          const float* __restrict__ was, const float* __restrict__ wad,
                          const float* __restrict__ bdots,
                          unsigned short* __restrict__ hb,
                          float* __restrict__ asrc, float* __restrict__ adst, int N) {
    constexpr int KF = K / 32;
    int wave = threadIdx.x >> 6;
    int lane = threadIdx.x & 63;
    int quad = lane >> 4;
    int r16 = lane & 15;
    int col = blockIdx.y * 16 + r16;

    short8 bfr[KF];
#pragma unroll
    for (int kk = 0; kk < KF; ++kk) {
        short8 b;
#pragma unroll
        for (int j = 0; j < 8; ++j)
            b[j] = (short)Wb[(kk * 32 + quad * 8 + j) * NOUT + col];
        bfr[kk] = b;
    }
    const bool dodots = (blockIdx.y == 0);
    float biasv = bias_add[col];
    int blockbase = blockIdx.x * 128;

#pragma unroll
    for (int rt = 0; rt < 2; ++rt) {
        int tilebase = blockbase + wave * 32 + rt * 16;
        if (tilebase >= N) break;                       // wave-uniform
        int arow = tilebase + r16;
        if (arow > N - 1) arow = N - 1;
        short8 afr[KF];
#pragma unroll
        for (int kk = 0; kk < KF; ++kk)
            afr[kk] = *(const short8*)(h2 + (long)arow * K + kk * 32 + quad * 8);
        floatx4 acc = {0.f, 0.f, 0.f, 0.f};
#pragma unroll
        for (int kk = 0; kk < KF; ++kk)
            acc = __builtin_amdgcn_mfma_f32_16x16x32_bf16(afr[kk], bfr[kk], acc, 0, 0, 0);
#pragma unroll
        for (int rr = 0; rr < 4; ++rr) {
            int srow = tilebase + quad * 4 + rr;
            if (srow < N) hb[(long)srow * NOUT + col] = f2bf(acc[rr] + biasv);
        }
        if (dodots) {
            float ds = 0.f, dd = 0.f;
#pragma unroll
            for (int kk = 0; kk < KF; ++kk) {
                int kb = kk * 32 + quad * 8;
#pragma unroll
                for (int j = 0; j < 8; ++j) {
                    float av = bf2f((unsigned short)afr[kk][j]);
                    ds += av * was[kb + j];
                    dd += av * wad[kb + j];
                }
            }
            ds += __shfl_xor(ds, 16, 64); ds += __shfl_xor(ds, 32, 64);
            dd += __shfl_xor(dd, 16, 64); dd += __shfl_xor(dd, 32, 64);
            int drow = tilebase + r16;
            if (quad == 0 && drow < N) {
                asrc[drow] = ds + bdots[0];
                adst[drow] = dd + bdots[1];
            }
        }
    }
}

// ---------------- fused softmax (no max-sub; scores bounded) + gather --------
template <int DOUT>
__global__ void gather_fused(const int* __restrict__ off,
                             const unsigned short* __restrict__ csr,
                             const float* __restrict__ asrc, const float* __restrict__ adst,
                             const unsigned short* __restrict__ hb,
                             const float* __restrict__ b,
                             unsigned short* __restrict__ out, int N) {
    constexpr int TPN = DOUT / 8;
    int t = blockIdx.x * blockDim.x + threadIdx.x;
    int d = t / TPN;
    if (d >= N) return;
    int l = t % TPN;
    int p0 = off[d], p1 = off[d + 1];
    float ad = adst[d];

    float sum = 0.f;
    for (int p = p0 + l; p < p1; p += TPN) {
        float e = asrc[csr[p]] + ad;
        e = e > 0.f ? e : 0.2f * e;              // leaky_relu(0.2)
        sum += __expf(e);
    }
#pragma unroll
    for (int o = TPN / 2; o > 0; o >>= 1) sum += __shfl_xor(sum, o, TPN);
    float inv = 1.f / sum;                        // self-loop guarantees sum > 0

    float acc[8];
#pragma unroll
    for (int i = 0; i < 8; ++i) acc[i] = 0.f;
    const int f0 = l * 8;

    for (int base = p0; base < p1; base += TPN) {
        int myp = base + l;
        float w = 0.f;
        int s = 0;
        if (myp < p1) {
            s = csr[myp];
            float e = asrc[s] + ad;
            e = e > 0.f ? e : 0.2f * e;
            w = __expf(e) * inv;
        }
        int rem = min(TPN, p1 - base);
        for (int j = 0; j < rem; ++j) {
            float aj = __shfl(w, j, TPN);
            int sj = __shfl(s, j, TPN);
            const uint4 hv = *(const uint4*)(hb + (long)sj * DOUT + f0);
            acc[0] += aj * bf2f((unsigned short)(hv.x & 0xffff));
            acc[1] += aj * bf2f((unsigned short)(hv.x >> 16));
            acc[2] += aj * bf2f((unsigned short)(hv.y & 0xffff));
            acc[3] += aj * bf2f((unsigned short)(hv.y >> 16));
            acc[4] += aj * bf2f((unsigned short)(hv.z & 0xffff));
            acc[5] += aj * bf2f((unsigned short)(hv.z >> 16));
            acc[6] += aj * bf2f((unsigned short)(hv.w & 0xffff));
            acc[7] += aj * bf2f((unsigned short)(hv.w >> 16));
        }
    }

    float4 b0 = *(const float4*)(b + f0);
    float4 b1 = *(const float4*)(b + f0 + 4);
    float bb[8] = {b0.x, b0.y, b0.z, b0.w, b1.x, b1.y, b1.z, b1.w};
    ushort4 o0, o1;
#pragma unroll
    for (int i = 0; i < 8; ++i) {
        float v = acc[i] + bb[i];
        v = v > 0.f ? v : 0.01f * v;             // leaky_relu(0.01)
        unsigned short hv = f2bf(v);
        if (i < 4) ((unsigned short*)&o0)[i] = hv;
        else       ((unsigned short*)&o1)[i - 4] = hv;
    }
    *(ushort4*)(out + (long)d * DOUT + f0) = o0;
    *(ushort4*)(out + (long)d * DOUT + f0 + 4) = o1;
}

// ---------------- BN statistics over bf16 activations ------------------------
template <int DOUT>
__global__ void stats_k(const unsigned short* __restrict__ y, float* __restrict__ bnsum,
                        float* __restrict__ bnsq, int N) {
    constexpr int QPR = DOUT / 8;
    __shared__ float ssum[DOUT];
    __shared__ float ssq[DOUT];
    for (int i = threadIdx.x; i < DOUT; i += blockDim.x) { ssum[i] = 0.f; ssq[i] = 0.f; }
    __syncthreads();
    long total = (long)N * QPR;
    long stride = (long)gridDim.x * blockDim.x;     // 120*256, multiple of QPR
    long t0 = (long)blockIdx.x * blockDim.x + threadIdx.x;
    int f0 = (int)(t0 % QPR) * 8;
    float ls[8], lq[8];
#pragma unroll
    for (int i = 0; i < 8; ++i) { ls[i] = 0.f; lq[i] = 0.f; }
    for (long t = t0; t < total; t += stride) {
        uint4 hv = *(const uint4*)(y + t * 8);
        unsigned vv[4] = {hv.x, hv.y, hv.z, hv.w};
#pragma unroll
        for (int q = 0; q < 4; ++q) {
            float v0 = bf2f((unsigned short)(vv[q] & 0xffff));
            float v1 = bf2f((unsigned short)(vv[q] >> 16));
            ls[2 * q] += v0;     lq[2 * q] += v0 * v0;
            ls[2 * q + 1] += v1; lq[2 * q + 1] += v1 * v1;
        }
    }
#pragma unroll
    for (int i = 0; i < 8; ++i) {
        atomicAdd(&ssum[f0 + i], ls[i]);
        atomicAdd(&ssq[f0 + i], lq[i]);
    }
    __syncthreads();
    for (int i = threadIdx.x; i < DOUT; i += blockDim.x) {
        atomicAdd(&bnsum[i], ssum[i]);
        atomicAdd(&bnsq[i], ssq[i]);
    }
}

// ---------------- pool with final BN computed inline -------------------------
__global__ void pool_bn2_k(const unsigned short* __restrict__ h, const int* __restrict__ gs,
                           const int* __restrict__ ge, const float* __restrict__ bnst,
                           const float* __restrict__ g4, const float* __restrict__ be4,
                           float invN, float* __restrict__ pooled) {
    int g = blockIdx.x;
    int f = threadIdx.x;                          // 64 threads
    float mu = bnst[f] * invN;
    float var = bnst[128 + f] * invN - mu * mu;
    float a = g4[f] * rsqrtf(var + 1e-5f);
    float c = be4[f] - mu * a;
    int s0 = gs[g], s1 = ge[g];
    float acc = 0.f, cnt = 0.f;
    if (s0 <= s1) {
        cnt = (float)(s1 - s0 + 1);
        for (int n = s0; n <= s1; ++n) acc += bf2f(h[(long)n * 64 + f]);
    }
    pooled[(long)g * 64 + f] = a * acc + cnt * c;
}

// ---------------- MLP head ----------------------------------------------------
__global__ void head_k(const float* __restrict__ pooled, const float* __restrict__ Wf,
                       const float* __restrict__ bf, const float* __restrict__ Wc,
                       const float* __restrict__ bc, float* __restrict__ out) {
    int g = blockIdx.x;
    int t = threadIdx.x;                          // 64 threads
    __shared__ float p[64];
    __shared__ float z[32];
    p[t] = pooled[(long)g * 64 + t];
    __syncthreads();
    if (t < 32) {
        float acc = bf[t];
#pragma unroll
        for (int f = 0; f < 64; ++f) acc += p[f] * Wf[f * 32 + t];
        z[t] = acc > 0.f ? acc : 0.01f * acc;
    }
    __syncthreads();
    if (t < 8) {
        float acc = bc[t];
#pragma unroll
        for (int o = 0; o < 32; ++o) acc += z[o] * Wc[o * 8 + t];
        out[(long)g * 8 + t] = 1.f / (1.f + __expf(-acc));
    }
}

extern "C" void kernel_launch(void* const* d_in, const int* in_sizes, int n_in,
                              void* d_out, int out_size, void* d_ws, size_t ws_size,
                              hipStream_t stream) {
    const float* x   = (const float*)d_in[0];
    const int* ei    = (const int*)d_in[1];
    const int* batch = (const int*)d_in[2];
    const int N  = in_sizes[2];
    const int E  = in_sizes[1] / 2;
    const int ET = E + N;
    const int G  = out_size / 8;
    const int* src = ei;
    const int* dst = ei + E;

    const float *W[4], *as_[4], *ad_[4], *bb[4], *gg[4], *be_[4];
    for (int i = 0; i < 4; ++i) {
        W[i]   = (const float*)d_in[3 + 6 * i];
        as_[i] = (const float*)d_in[4 + 6 * i];
        ad_[i] = (const float*)d_in[5 + 6 * i];
        bb[i]  = (const float*)d_in[6 + 6 * i];
        gg[i]  = (const float*)d_in[7 + 6 * i];
        be_[i] = (const float*)d_in[8 + 6 * i];
    }
    const float* Wf = (const float*)d_in[27];
    const float* bf = (const float*)d_in[28];
    const float* Wc = (const float*)d_in[29];
    const float* bc = (const float*)d_in[30];

    float* ws = (float*)d_ws;
    long off_ = 0;
    auto alloc = [&](long nelem) { float* p = ws + off_; off_ += (nelem + 3) & ~3L; return p; };
    unsigned short* h2a = (unsigned short*)alloc((long)N * 64);  // N x 128 bf16
    unsigned short* h2b = (unsigned short*)alloc((long)N * 64);
    unsigned short* hb  = (unsigned short*)alloc((long)N * 64);
    unsigned short* Wb  = (unsigned short*)alloc(8192);          // 128x128 bf16
    float* bias_add = alloc(128);
    float* was      = alloc(128);
    float* wad      = alloc(128);
    float* bdots    = alloc(4);
    float* asrc     = alloc(N);
    float* adst     = alloc(N);
    float* bnstats  = alloc(4 * 256);       // per-layer: sum[128] | sq[128]
    float* pooled   = alloc((long)G * 64);
    unsigned* ebkt  = (unsigned*)alloc(E);
    int* histg      = (int*)alloc((long)NBLKA * 256);
    int* bucket_base = (int*)alloc(260);
    int* off        = (int*)alloc(N + 1);
    unsigned short* csr = (unsigned short*)alloc(ET / 2 + 2);
    int* gs         = (int*)alloc(G);
    int* ge         = (int*)alloc(G);
    (void)ws_size; (void)n_in;

    const int nbkt = cdiv(N, 256);          // 196
    const int chunk = cdiv(E, NBLKA);
    const float invN = 1.f / (float)N;

    // ---- input cast + CSR build (bucket sort, no global atomics) ----
    cast_bf16_k<<<cdiv((long)N * 32, BLK), BLK, 0, stream>>>(x, h2a, (long)N * 32);
    histA_k<<<NBLKA, BLK, 0, stream>>>(dst, histg, E, nbkt, chunk);
    bucket_scan_k<<<1, BLK, 0, stream>>>(histg, bucket_base, nbkt, E, gs, ge, G);
    blk_scan_k<<<nbkt, BLK, 0, stream>>>(histg, bucket_base, nbkt);
    scatterA_k<<<NBLKA, BLK, 0, stream>>>(src, dst, histg, ebkt, E, nbkt, chunk);
    csrB_k<<<nbkt, BLK, 0, stream>>>(ebkt, bucket_base, off, csr, N, E, nbkt);
    grange2_k<<<cdiv(N, BLK), BLK, 0, stream>>>(batch, gs, ge, N);
    hipMemsetAsync(bnstats, 0, 4 * 256 * sizeof(float), stream);

#define LAYER(i, DIN, DOUT, INP, OUTP, BNPREV, GPREV, BEPREV)                             \
    do {                                                                                  \
        prep_k<<<1, BLK, 0, stream>>>(W[i], as_[i], ad_[i], BNPREV, GPREV, BEPREV, invN,  \
                                      Wb, bias_add, was, wad, bdots, DIN, DOUT);          \
        gemm_mfma<DIN, DOUT><<<dim3(cdiv(N, 128), DOUT / 16), 256, 0, stream>>>(          \
            INP, Wb, bias_add, was, wad, bdots, hb, asrc, adst, N);                       \
        gather_fused<DOUT><<<cdiv((long)N * (DOUT / 8), BLK), BLK, 0, stream>>>(          \
            off, csr, asrc, adst, hb, bb[i], OUTP, N);                                    \
        stats_k<DOUT><<<120, BLK, 0, stream>>>(OUTP, bnstats + i * 256,                   \
                                               bnstats + i * 256 + 128, N);               \
    } while (0)

    LAYER(0, 128, 32, h2a, h2b, (const float*)nullptr, (const float*)nullptr,
          (const float*)nullptr);
    LAYER(1, 32, 64, h2b, h2a, bnstats + 0 * 256, gg[0], be_[0]);
    LAYER(2, 64, 128, h2a, h2b, bnstats + 1 * 256, gg[1], be_[1]);
    LAYER(3, 128, 64, h2b, h2a, bnstats + 2 * 256, gg[2], be_[2]);
#undef LAYER

    pool_bn2_k<<<G, 64, 0, stream>>>(h2a, gs, ge, bnstats + 3 * 256, gg[3], be_[3],
                                     invN, pooled);
    head_k<<<G, 64, 0, stream>>>(pooled, Wf, bf, Wc, bc, (float*)d_out);
}

// Round 6
// 451.797 us; speedup vs baseline: 9.0037x; 1.0199x over previous
//
#include <hip/hip_runtime.h>
#include <math.h>

constexpr int BLK = 256;
constexpr int NBLKA = 256;     // phase-A blocks for edge bucketing

static inline int cdiv(long a, long b) { return (int)((a + b - 1) / b); }

typedef __attribute__((ext_vector_type(8))) short short8;
typedef __attribute__((ext_vector_type(4))) float floatx4;

// ---------------- bf16 helpers (RNE) -----------------------------------------
__device__ __forceinline__ unsigned short f2bf(float f) {
    unsigned u = __float_as_uint(f);
    unsigned r = u + 0x7fffu + ((u >> 16) & 1u);
    return (unsigned short)(r >> 16);
}
__device__ __forceinline__ float bf2f(unsigned short s) {
    return __uint_as_float(((unsigned)s) << 16);
}

// ============== CSR build via 2-phase bucket sort (NO global atomics) ========
// Bucket b covers nodes [b*256, b*256+256). histg layout: [z*nbkt + b].

__global__ void histA_k(const int* __restrict__ dst, int* __restrict__ histg,
                        int E, int nbkt, int chunk) {
    __shared__ int h[256];
    int tid = threadIdx.x, z = blockIdx.x;
    h[tid] = 0;
    __syncthreads();
    int e0 = z * chunk, e1 = min(E, e0 + chunk);
    for (int e = e0 + tid; e < e1; e += BLK) atomicAdd(&h[dst[e] >> 8], 1);
    __syncthreads();
    if (tid < nbkt) histg[z * nbkt + tid] = h[tid];
}

__global__ void bucket_scan_k(const int* __restrict__ histg, int* __restrict__ bucket_base,
                              int nbkt, int E, int* __restrict__ gs, int* __restrict__ ge,
                              int G) {
    __shared__ int s[BLK];
    int t = threadIdx.x;
    int v = 0;
    if (t < nbkt)
        for (int z = 0; z < NBLKA; ++z) v += histg[z * nbkt + t];
    s[t] = v;
    __syncthreads();
    for (int o = 1; o < BLK; o <<= 1) {
        int tv = (t >= o) ? s[t - o] : 0;
        __syncthreads();
        s[t] += tv;
        __syncthreads();
    }
    if (t < nbkt) bucket_base[t] = s[t] - v;
    if (t == 0) bucket_base[nbkt] = E;
    for (int i = t; i < G; i += BLK) { gs[i] = 0x7fffffff; ge[i] = -1; }
}

__global__ void blk_scan_k(int* __restrict__ histg, const int* __restrict__ bucket_base,
                           int nbkt) {
    __shared__ int s[BLK];
    int t = threadIdx.x, b = blockIdx.x;
    int v = histg[t * nbkt + b];
    s[t] = v;
    __syncthreads();
    for (int o = 1; o < BLK; o <<= 1) {
        int tv = (t >= o) ? s[t - o] : 0;
        __syncthreads();
        s[t] += tv;
        __syncthreads();
    }
    histg[t * nbkt + b] = bucket_base[b] + s[t] - v;
}

__global__ void scatterA_k(const int* __restrict__ src, const int* __restrict__ dst,
                           const int* __restrict__ histg, unsigned* __restrict__ ebkt,
                           int E, int nbkt, int chunk) {
    __shared__ int cur[256];
    int tid = threadIdx.x, z = blockIdx.x;
    if (tid < nbkt) cur[tid] = histg[z * nbkt + tid];
    __syncthreads();
    int e0 = z * chunk, e1 = min(E, e0 + chunk);
    for (int e = e0 + tid; e < e1; e += BLK) {
        int d = dst[e];
        int b = d >> 8;
        int pos = atomicAdd(&cur[b], 1);
        ebkt[pos] = ((unsigned)(d & 255) << 16) | (unsigned)src[e];
    }
}

// B: per-bucket CSR finalize (degrees->scan->self-loop->fill) + graph ranges.
__global__ void csrB_k(const unsigned* __restrict__ ebkt, const int* __restrict__ bucket_base,
                       int* __restrict__ off, unsigned short* __restrict__ csr,
                       const int* __restrict__ batch, int* __restrict__ gs,
                       int* __restrict__ ge, int N, int E, int nbkt) {
    __shared__ int dg[256];
    __shared__ int sc[256];
    int t = threadIdx.x, b = blockIdx.x;
    int n0 = b << 8;
    int cnt = min(256, N - n0);
    dg[t] = (t < cnt) ? 1 : 0;                     // self-loop
    __syncthreads();
    int e0 = bucket_base[b], e1 = bucket_base[b + 1];
    for (int e = e0 + t; e < e1; e += BLK) atomicAdd(&dg[ebkt[e] >> 16], 1);
    __syncthreads();
    int d = dg[t];
    sc[t] = d;
    __syncthreads();
    for (int o = 1; o < BLK; o <<= 1) {
        int tv = (t >= o) ? sc[t - o] : 0;
        __syncthreads();
        sc[t] += tv;
        __syncthreads();
    }
    int loff = sc[t] - d;                          // exclusive
    int csrbase = e0 + n0;                         // n0 self-loops precede bucket
    if (t < cnt) {
        off[n0 + t] = csrbase + loff;
        csr[csrbase + loff] = (unsigned short)(n0 + t);   // self-loop slot
        dg[t] = loff + 1;                          // cursor
    }
    if (b == nbkt - 1 && t == 0) off[N] = E + N;
    // graph ranges (batch sorted): boundary detection, this grid covers N.
    int n = n0 + t;
    if (n < N) {
        int bb = batch[n];
        if (n == 0) gs[bb] = 0;
        else {
            int pb = batch[n - 1];
            if (pb != bb) { gs[bb] = n; ge[pb] = n - 1; }
        }
        if (n == N - 1) ge[bb] = N - 1;
    }
    __syncthreads();
    for (int e = e0 + t; e < e1; e += BLK) {
        unsigned w = ebkt[e];
        int pos = atomicAdd(&dg[w >> 16], 1);
        csr[csrbase + pos] = (unsigned short)(w & 0xffff);
    }
}

// ---------------- per-layer prep (slim): BN coefs + fold vectors -------------
// ca[k]=a (BN scale of prev layer, 1 if none), bias_add[f]=sum_k c[k]W[k][f],
// was[k]=a[k](W[k,:]@a_s), wad likewise, bdots = bias_add @ {a_s, a_d}.
__global__ void prep_k(const float* __restrict__ W, const float* __restrict__ a_s,
                       const float* __restrict__ a_d, const float* __restrict__ bnst,
                       const float* __restrict__ g_prev, const float* __restrict__ be_prev,
                       float invN, float* __restrict__ ca_out, float* __restrict__ bias_add,
                       float* __restrict__ was, float* __restrict__ wad,
                       float* __restrict__ bdots, int K, int Nout) {
    __shared__ float ca[128], cc[128], lb[128];
    int tid = threadIdx.x;
    if (tid < K) {
        float a = 1.f, c = 0.f;
        if (bnst) {
            float mu = bnst[tid] * invN;
            float var = bnst[128 + tid] * invN - mu * mu;
            a = g_prev[tid] * rsqrtf(var + 1e-5f);
            c = be_prev[tid] - mu * a;
        }
        ca[tid] = a; cc[tid] = c;
        ca_out[tid] = a;
    }
    __syncthreads();
    for (int f = tid; f < Nout; f += BLK) {
        float s = 0.f;
        for (int k = 0; k < K; ++k) s += cc[k] * W[k * Nout + f];
        bias_add[f] = s;
        lb[f] = s;
    }
    for (int k = tid; k < K; k += BLK) {
        float s1 = 0.f, s2 = 0.f;
        for (int f = 0; f < Nout; ++f) {
            float w = W[k * Nout + f];
            s1 += w * a_s[f];
            s2 += w * a_d[f];
        }
        was[k] = ca[k] * s1;
        wad[k] = ca[k] * s2;
    }
    __syncthreads();
    if (tid == 0) {
        float s1 = 0.f, s2 = 0.f;
        for (int f = 0; f < Nout; ++f) {
            s1 += lb[f] * a_s[f];
            s2 += lb[f] * a_d[f];
        }
        bdots[0] = s1;
        bdots[1] = s2;
    }
}

// ---------------- MFMA GEMM: hb = act @ (ca.W) + bias_add, + attn dots -------
// W converted fp32->bf16 inline (ca staged in LDS); A from bf16 h2 or fp32 x.
template <int K, int NOUT, bool AFP32>
__launch_bounds__(256)
__global__ void gemm_mfma(const void* __restrict__ av, const float* __restrict__ W,
                          const float* __restrict__ ca_in,
                          const float* __restrict__ bias_add,
                          const float* __restrict__ was, const float* __restrict__ wad,
                          const float* __restrict__ bdots,
                          unsigned short* __restrict__ hb,
                          float* __restrict__ asrc, float* __restrict__ adst, int N) {
    constexpr int KF = K / 32;
    __shared__ float sca[K];
    if (threadIdx.x < K) sca[threadIdx.x] = ca_in[threadIdx.x];
    __syncthreads();

    int wave = threadIdx.x >> 6;
    int lane = threadIdx.x & 63;
    int quad = lane >> 4;
    int r16 = lane & 15;
    int col = blockIdx.y * 16 + r16;

    short8 bfr[KF];
#pragma unroll
    for (int kk = 0; kk < KF; ++kk) {
        short8 b;
#pragma unroll
        for (int j = 0; j < 8; ++j) {
            int k = kk * 32 + quad * 8 + j;
            b[j] = (short)f2bf(sca[k] * W[(long)k * NOUT + col]);
        }
        bfr[kk] = b;
    }
    const bool dodots = (blockIdx.y == 0);
    float biasv = bias_add[col];
    int blockbase = blockIdx.x * 128;

#pragma unroll
    for (int rt = 0; rt < 2; ++rt) {
        int tilebase = blockbase + wave * 32 + rt * 16;
        if (tilebase >= N) break;                       // wave-uniform
        int arow = tilebase + r16;
        if (arow > N - 1) arow = N - 1;
        short8 afr[KF];
        if (AFP32) {
            const float* xr = (const float*)av + (long)arow * K;
#pragma unroll
            for (int kk = 0; kk < KF; ++kk) {
                float4 x0 = *(const float4*)(xr + kk * 32 + quad * 8);
                float4 x1 = *(const float4*)(xr + kk * 32 + quad * 8 + 4);
                short8 a;
                a[0] = (short)f2bf(x0.x); a[1] = (short)f2bf(x0.y);
                a[2] = (short)f2bf(x0.z); a[3] = (short)f2bf(x0.w);
                a[4] = (short)f2bf(x1.x); a[5] = (short)f2bf(x1.y);
                a[6] = (short)f2bf(x1.z); a[7] = (short)f2bf(x1.w);
                afr[kk] = a;
            }
        } else {
            const unsigned short* hr = (const unsigned short*)av + (long)arow * K;
#pragma unroll
            for (int kk = 0; kk < KF; ++kk)
                afr[kk] = *(const short8*)(hr + kk * 32 + quad * 8);
        }
        floatx4 acc = {0.f, 0.f, 0.f, 0.f};
#pragma unroll
        for (int kk = 0; kk < KF; ++kk)
            acc = __builtin_amdgcn_mfma_f32_16x16x32_bf16(afr[kk], bfr[kk], acc, 0, 0, 0);
#pragma unroll
        for (int rr = 0; rr < 4; ++rr) {
            int srow = tilebase + quad * 4 + rr;
            if (srow < N) hb[(long)srow * NOUT + col] = f2bf(acc[rr] + biasv);
        }
        if (dodots) {
            float ds = 0.f, dd = 0.f;
#pragma unroll
            for (int kk = 0; kk < KF; ++kk) {
                int kb = kk * 32 + quad * 8;
#pragma unroll
                for (int j = 0; j < 8; ++j) {
                    float a = bf2f((unsigned short)afr[kk][j]);
                    ds += a * was[kb + j];
                    dd += a * wad[kb + j];
                }
            }
            ds += __shfl_xor(ds, 16, 64); ds += __shfl_xor(ds, 32, 64);
            dd += __shfl_xor(dd, 16, 64); dd += __shfl_xor(dd, 32, 64);
            int drow = tilebase + r16;
            if (quad == 0 && drow < N) {
                asrc[drow] = ds + bdots[0];
                adst[drow] = dd + bdots[1];
            }
        }
    }
}

// ---------------- fused softmax (no max-sub; scores bounded) + gather --------
template <int DOUT>
__global__ void gather_fused(const int* __restrict__ off,
                             const unsigned short* __restrict__ csr,
                             const float* __restrict__ asrc, const float* __restrict__ adst,
                             const unsigned short* __restrict__ hb,
                             const float* __restrict__ b,
                             unsigned short* __restrict__ out, int N) {
    constexpr int TPN = DOUT / 8;
    int t = blockIdx.x * blockDim.x + threadIdx.x;
    int d = t / TPN;
    if (d >= N) return;
    int l = t % TPN;
    int p0 = off[d], p1 = off[d + 1];
    float ad = adst[d];

    float sum = 0.f;
    for (int p = p0 + l; p < p1; p += TPN) {
        float e = asrc[csr[p]] + ad;
        e = e > 0.f ? e : 0.2f * e;              // leaky_relu(0.2)
        sum += __expf(e);
    }
#pragma unroll
    for (int o = TPN / 2; o > 0; o >>= 1) sum += __shfl_xor(sum, o, TPN);
    float inv = 1.f / sum;                        // self-loop guarantees sum > 0

    float acc[8];
#pragma unroll
    for (int i = 0; i < 8; ++i) acc[i] = 0.f;
    const int f0 = l * 8;

    for (int base = p0; base < p1; base += TPN) {
        int myp = base + l;
        float w = 0.f;
        int s = 0;
        if (myp < p1) {
            s = csr[myp];
            float e = asrc[s] + ad;
            e = e > 0.f ? e : 0.2f * e;
            w = __expf(e) * inv;
        }
        int rem = min(TPN, p1 - base);
        for (int j = 0; j < rem; ++j) {
            float aj = __shfl(w, j, TPN);
            int sj = __shfl(s, j, TPN);
            const uint4 hv = *(const uint4*)(hb + (long)sj * DOUT + f0);
            acc[0] += aj * bf2f((unsigned short)(hv.x & 0xffff));
            acc[1] += aj * bf2f((unsigned short)(hv.x >> 16));
            acc[2] += aj * bf2f((unsigned short)(hv.y & 0xffff));
            acc[3] += aj * bf2f((unsigned short)(hv.y >> 16));
            acc[4] += aj * bf2f((unsigned short)(hv.z & 0xffff));
            acc[5] += aj * bf2f((unsigned short)(hv.z >> 16));
            acc[6] += aj * bf2f((unsigned short)(hv.w & 0xffff));
            acc[7] += aj * bf2f((unsigned short)(hv.w >> 16));
        }
    }

    float4 b0 = *(const float4*)(b + f0);
    float4 b1 = *(const float4*)(b + f0 + 4);
    float bb[8] = {b0.x, b0.y, b0.z, b0.w, b1.x, b1.y, b1.z, b1.w};
    ushort4 o0, o1;
#pragma unroll
    for (int i = 0; i < 8; ++i) {
        float v = acc[i] + bb[i];
        v = v > 0.f ? v : 0.01f * v;             // leaky_relu(0.01)
        unsigned short hv = f2bf(v);
        if (i < 4) ((unsigned short*)&o0)[i] = hv;
        else       ((unsigned short*)&o1)[i - 4] = hv;
    }
    *(ushort4*)(out + (long)d * DOUT + f0) = o0;
    *(ushort4*)(out + (long)d * DOUT + f0 + 4) = o1;
}

// ---------------- BN statistics over bf16 activations ------------------------
template <int DOUT>
__global__ void stats_k(const unsigned short* __restrict__ y, float* __restrict__ bnsum,
                        float* __restrict__ bnsq, int N) {
    constexpr int QPR = DOUT / 8;
    __shared__ float ssum[DOUT];
    __shared__ float ssq[DOUT];
    for (int i = threadIdx.x; i < DOUT; i += blockDim.x) { ssum[i] = 0.f; ssq[i] = 0.f; }
    __syncthreads();
    long total = (long)N * QPR;
    long stride = (long)gridDim.x * blockDim.x;     // multiple of QPR
    long t0 = (long)blockIdx.x * blockDim.x + threadIdx.x;
    int f0 = (int)(t0 % QPR) * 8;
    float ls[8], lq[8];
#pragma unroll
    for (int i = 0; i < 8; ++i) { ls[i] = 0.f; lq[i] = 0.f; }
    for (long t = t0; t < total; t += stride) {
        uint4 hv = *(const uint4*)(y + t * 8);
        unsigned vv[4] = {hv.x, hv.y, hv.z, hv.w};
#pragma unroll
        for (int q = 0; q < 4; ++q) {
            float v0 = bf2f((unsigned short)(vv[q] & 0xffff));
            float v1 = bf2f((unsigned short)(vv[q] >> 16));
            ls[2 * q] += v0;     lq[2 * q] += v0 * v0;
            ls[2 * q + 1] += v1; lq[2 * q + 1] += v1 * v1;
        }
    }
#pragma unroll
    for (int i = 0; i < 8; ++i) {
        atomicAdd(&ssum[f0 + i], ls[i]);
        atomicAdd(&ssq[f0 + i], lq[i]);
    }
    __syncthreads();
    for (int i = threadIdx.x; i < DOUT; i += blockDim.x) {
        atomicAdd(&bnsum[i], ssum[i]);
        atomicAdd(&bnsq[i], ssq[i]);
    }
}

// ---------------- pool (with inline final BN) + MLP head, fused --------------
__global__ void pool_head_k(const unsigned short* __restrict__ h, const int* __restrict__ gs,
                            const int* __restrict__ ge, const float* __restrict__ bnst,
                            const float* __restrict__ g4, const float* __restrict__ be4,
                            float invN, const float* __restrict__ Wf,
                            const float* __restrict__ bf, const float* __restrict__ Wc,
                            const float* __restrict__ bc, float* __restrict__ out) {
    int g = blockIdx.x;
    int t = threadIdx.x;                          // 64 threads
    __shared__ float p[64];
    __shared__ float z[32];
    float mu = bnst[t] * invN;
    float var = bnst[128 + t] * invN - mu * mu;
    float a = g4[t] * rsqrtf(var + 1e-5f);
    float c = be4[t] - mu * a;
    int s0 = gs[g], s1 = ge[g];
    float acc = 0.f, cnt = 0.f;
    if (s0 <= s1) {
        cnt = (float)(s1 - s0 + 1);
        for (int n = s0; n <= s1; ++n) acc += bf2f(h[(long)n * 64 + t]);
    }
    p[t] = a * acc + cnt * c;
    __syncthreads();
    if (t < 32) {
        float zacc = bf[t];
#pragma unroll
        for (int f = 0; f < 64; ++f) zacc += p[f] * Wf[f * 32 + t];
        z[t] = zacc > 0.f ? zacc : 0.01f * zacc;
    }
    __syncthreads();
    if (t < 8) {
        float oacc = bc[t];
#pragma unroll
        for (int o = 0; o < 32; ++o) oacc += z[o] * Wc[o * 8 + t];
        out[(long)g * 8 + t] = 1.f / (1.f + __expf(-oacc));
    }
}

extern "C" void kernel_launch(void* const* d_in, const int* in_sizes, int n_in,
                              void* d_out, int out_size, void* d_ws, size_t ws_size,
                              hipStream_t stream) {
    const float* x   = (const float*)d_in[0];
    const int* ei    = (const int*)d_in[1];
    const int* batch = (const int*)d_in[2];
    const int N  = in_sizes[2];
    const int E  = in_sizes[1] / 2;
    const int ET = E + N;
    const int G  = out_size / 8;
    const int* src = ei;
    const int* dst = ei + E;

    const float *W[4], *as_[4], *ad_[4], *bb[4], *gg[4], *be_[4];
    for (int i = 0; i < 4; ++i) {
        W[i]   = (const float*)d_in[3 + 6 * i];
        as_[i] = (const float*)d_in[4 + 6 * i];
        ad_[i] = (const float*)d_in[5 + 6 * i];
        bb[i]  = (const float*)d_in[6 + 6 * i];
        gg[i]  = (const float*)d_in[7 + 6 * i];
        be_[i] = (const float*)d_in[8 + 6 * i];
    }
    const float* Wf = (const float*)d_in[27];
    const float* bfp = (const float*)d_in[28];
    const float* Wc = (const float*)d_in[29];
    const float* bc = (const float*)d_in[30];

    float* ws = (float*)d_ws;
    long off_ = 0;
    auto alloc = [&](long nelem) { float* p = ws + off_; off_ += (nelem + 3) & ~3L; return p; };
    unsigned short* h2a = (unsigned short*)alloc((long)N * 64);  // N x 128 bf16
    unsigned short* h2b = (unsigned short*)alloc((long)N * 64);
    unsigned short* hb  = (unsigned short*)alloc((long)N * 64);
    float* ca       = alloc(128);
    float* bias_add = alloc(128);
    float* was      = alloc(128);
    float* wad      = alloc(128);
    float* bdots    = alloc(4);
    float* asrc     = alloc(N);
    float* adst     = alloc(N);
    float* bnstats  = alloc(4 * 256);       // per-layer: sum[128] | sq[128]
    unsigned* ebkt  = (unsigned*)alloc(E);
    int* histg      = (int*)alloc((long)NBLKA * 256);
    int* bucket_base = (int*)alloc(260);
    int* off        = (int*)alloc(N + 1);
    unsigned short* csr = (unsigned short*)alloc(ET / 2 + 2);
    int* gs         = (int*)alloc(G);
    int* ge         = (int*)alloc(G);
    (void)ws_size; (void)n_in;

    const int nbkt = cdiv(N, 256);          // 196
    const int chunk = cdiv(E, NBLKA);
    const float invN = 1.f / (float)N;

    // ---- CSR build (bucket sort, no global atomics) + graph ranges ----
    histA_k<<<NBLKA, BLK, 0, stream>>>(dst, histg, E, nbkt, chunk);
    bucket_scan_k<<<1, BLK, 0, stream>>>(histg, bucket_base, nbkt, E, gs, ge, G);
    blk_scan_k<<<nbkt, BLK, 0, stream>>>(histg, bucket_base, nbkt);
    scatterA_k<<<NBLKA, BLK, 0, stream>>>(src, dst, histg, ebkt, E, nbkt, chunk);
    csrB_k<<<nbkt, BLK, 0, stream>>>(ebkt, bucket_base, off, csr, batch, gs, ge, N, E, nbkt);
    hipMemsetAsync(bnstats, 0, 4 * 256 * sizeof(float), stream);

#define LAYER(i, DIN, DOUT, AFP32, INP, OUTP, BNPREV, GPREV, BEPREV)                      \
    do {                                                                                  \
        prep_k<<<1, BLK, 0, stream>>>(W[i], as_[i], ad_[i], BNPREV, GPREV, BEPREV, invN,  \
                                      ca, bias_add, was, wad, bdots, DIN, DOUT);          \
        gemm_mfma<DIN, DOUT, AFP32><<<dim3(cdiv(N, 128), DOUT / 16), 256, 0, stream>>>(   \
            INP, W[i], ca, bias_add, was, wad, bdots, hb, asrc, adst, N);                 \
        gather_fused<DOUT><<<cdiv((long)N * (DOUT / 8), BLK), BLK, 0, stream>>>(          \
            off, csr, asrc, adst, hb, bb[i], OUTP, N);                                    \
        stats_k<DOUT><<<120, BLK, 0, stream>>>(OUTP, bnstats + i * 256,                   \
                                               bnstats + i * 256 + 128, N);               \
    } while (0)

    LAYER(0, 128, 32, true, x, h2b, (const float*)nullptr, (const float*)nullptr,
          (const float*)nullptr);
    LAYER(1, 32, 64, false, h2b, h2a, bnstats + 0 * 256, gg[0], be_[0]);
    LAYER(2, 64, 128, false, h2a, h2b, bnstats + 1 * 256, gg[1], be_[1]);
    LAYER(3, 128, 64, false, h2b, h2a, bnstats + 2 * 256, gg[2], be_[2]);
#undef LAYER

    pool_head_k<<<G, 64, 0, stream>>>(h2a, gs, ge, bnstats + 3 * 256, gg[3], be_[3],
                                      invN, Wf, bfp, Wc, bc, (float*)d_out);
}